// Round 16
// baseline (2872.514 us; speedup 1.0000x reference)
//
#include <hip/hip_runtime.h>
#include <hip/hip_bf16.h>
#include <math.h>

// ---------------------------------------------------------------------------
// UniversalReasoner: 8-step recurrent transformer + vocab decoder, MI355X.
// Round 16: k_gemm ks1-read pre-issue — all 24 ds_reads issued before the
// ks0 MFMA cluster so ks1's LDS latency hides under ks0 MFMAs (compiler
// emits the counted lgkmcnt for ks0 only; barrier placement unchanged).
// k_dec deliberately untouched (VGPR headroom hedge + within-run control).
// Everything else identical to R15.
// ---------------------------------------------------------------------------

typedef float  f32x4  __attribute__((ext_vector_type(4)));
typedef __bf16 bf16x8 __attribute__((ext_vector_type(8)));
typedef __bf16 bf16x4 __attribute__((ext_vector_type(4)));

static constexpr int BB   = 16;     // batch
static constexpr int S    = 128;    // sequence tokens
static constexpr int SCR  = 64;     // scratch tokens
static constexpr int T    = 192;    // S + SCR
static constexpr int D    = 1024;
static constexpr int H    = 8;
static constexpr int HD   = 128;
static constexpr int DFF  = 4096;
static constexpr int NSTEP= 8;
static constexpr int V    = 100277;
static constexpr int ROWS = BB * T; // 3072
static constexpr int MD   = BB * S; // 2048 decoder rows
static constexpr long long LOGITS = (long long)BB * S * V; // 205367296
static constexpr size_t QSZ = (size_t)BB * H * T * HD;     // per q/k/v tensor

#define DEV __device__ __forceinline__

DEV void gload16(const __bf16* g, __bf16* l) {
  __builtin_amdgcn_global_load_lds(
      (__attribute__((address_space(1))) void*)(g),
      (__attribute__((address_space(3))) void*)(l), 16, 0, 0);
}

// ---------------------------------------------------------------------------
// Workhorse GEMM (128x128x64):  C[M,N] = A[M,K] * Bt[N,K]^T (+epilogue)
// EPI: 1 = bias + in-place f32 residual add ; 2 = bias + gelu -> bf16 ;
//      4 = split-K: bz = k-chunk, atomicAdd into f32 C, bias only on bz==0 ;
//      5 = QKV+rope: writes q/k bf16 (rope'd) and vT bf16 via kind = tn>>10.
// Requires K % 64 == 0. Launch with 65536 B dynamic LDS.
// ---------------------------------------------------------------------------
template <int EPI>
__global__ __launch_bounds__(256) void k_gemm(
    const __bf16* __restrict__ A, long long sA, int ldA, int M,
    const __bf16* __restrict__ Bt, long long sB, int ldB, int N, int K,
    const float* __restrict__ bias, void* __restrict__ C, long long sC,
    int ldC, const float* __restrict__ rct, const float* __restrict__ rst) {
  extern __shared__ char smem[];
  __bf16* lds = (__bf16*)smem;   // A(buf)=lds+buf*16384; B(buf)=+8192

  const int bz = blockIdx.z;
  const __bf16* Ab;
  const __bf16* Bb;
  if constexpr (EPI == 4) {
    Ab = A + (size_t)bz * K;   // k-chunk offset within row
    Bb = Bt + (size_t)bz * K;
  } else {
    Ab = A + (size_t)bz * sA;
    Bb = Bt + (size_t)bz * sB;
  }
  const int tm = blockIdx.y * 128, tn = blockIdx.x * 128;
  const int tid = threadIdx.x;
  const int lane = tid & 63, wv = tid >> 6;
  const int wr = wv >> 1, wc = wv & 1;  // 2x2 wave grid, 64x64 per wave
  const int g4 = lane >> 4, l15 = lane & 15;

  f32x4 acc[4][4];
#pragma unroll
  for (int m = 0; m < 4; m++)
#pragma unroll
    for (int n = 0; n < 4; n++) acc[m][n] = (f32x4)(0.f);

  // staging: chunk = i*256+tid -> local row = i*32 + (tid>>3), phys slot tid&7
  const int srow = tid >> 3;                          // 0..31
  const int lcol = (((tid & 7) ^ (srow & 7)) * 8);    // pre-swizzled k offset
  int arows[4], brows[4];
#pragma unroll
  for (int i = 0; i < 4; i++) {
    int ar = tm + i * 32 + srow; if (ar > M - 1) ar = M - 1;
    int br = tn + i * 32 + srow; if (br > N - 1) br = N - 1;
    arows[i] = ar; brows[i] = br;
  }

  auto stage = [&](int buf, int kk) {
    __bf16* Abuf = lds + buf * 16384;
    __bf16* Bbuf = lds + 8192 + buf * 16384;
#pragma unroll
    for (int i = 0; i < 4; i++)
      gload16(Ab + (size_t)arows[i] * ldA + kk + lcol, Abuf + i * 2048 + (size_t)tid * 8);
#pragma unroll
    for (int i = 0; i < 4; i++)
      gload16(Bb + (size_t)brows[i] * ldB + kk + lcol, Bbuf + i * 2048 + (size_t)tid * 8);
  };

  // one K-tile (64 wide): pre-issue ALL 24 ds_reads, then 2 MFMA clusters.
  // ks1's read latency hides under the ks0 cluster; barrier unchanged
  // (after lgkmcnt(0), before ks1 MFMA -> buffer safe to overwrite).
  auto compute = [&](int cur) {
    const __bf16* Abuf = lds + cur * 16384;
    const __bf16* Bbuf = lds + 8192 + cur * 16384;
    bf16x8 a0[4], b0[4], a1[4], b1[4];
#pragma unroll
    for (int m = 0; m < 4; m++) {
      const int row = wr * 64 + m * 16 + l15;
      a0[m] = *(const bf16x8*)&Abuf[row * 64 + (g4 ^ (row & 7)) * 8];
      a1[m] = *(const bf16x8*)&Abuf[row * 64 + ((4 + g4) ^ (row & 7)) * 8];
    }
#pragma unroll
    for (int n = 0; n < 4; n++) {
      const int row = wc * 64 + n * 16 + l15;
      b0[n] = *(const bf16x8*)&Bbuf[row * 64 + (g4 ^ (row & 7)) * 8];
      b1[n] = *(const bf16x8*)&Bbuf[row * 64 + ((4 + g4) ^ (row & 7)) * 8];
    }
    __builtin_amdgcn_sched_barrier(0);   // pin: all reads issued first
#pragma unroll
    for (int m = 0; m < 4; m++)
#pragma unroll
      for (int n = 0; n < 4; n++)
        acc[m][n] = __builtin_amdgcn_mfma_f32_16x16x32_bf16(a0[m], b0[n],
                                                            acc[m][n], 0, 0, 0);
    asm volatile("s_waitcnt lgkmcnt(0)" ::: "memory");
    __builtin_amdgcn_sched_barrier(0);
    __builtin_amdgcn_s_barrier();   // all waves done reading buf[cur]
#pragma unroll
    for (int m = 0; m < 4; m++)
#pragma unroll
      for (int n = 0; n < 4; n++)
        acc[m][n] = __builtin_amdgcn_mfma_f32_16x16x32_bf16(a1[m], b1[n],
                                                            acc[m][n], 0, 0, 0);
  };

  const int NT = K >> 6;           // K-tiles of 64 (K % 64 == 0)
  stage(0, 0);
  for (int it = 0; it < NT - 1; ++it) {
    const int cur = it & 1;
    stage(cur ^ 1, (it + 1) << 6);                    // 8 loads in flight
    asm volatile("s_waitcnt vmcnt(8)" ::: "memory");  // tile-cur loads landed
    __builtin_amdgcn_s_barrier();
    compute(cur);
  }
  asm volatile("s_waitcnt vmcnt(0)" ::: "memory");
  __builtin_amdgcn_s_barrier();
  compute((NT - 1) & 1);

  // epilogue: C/D layout col=lane&15, row=(lane>>4)*4+reg
  const int r0 = tm + wr * 64, c0 = tn + wc * 64;
  if constexpr (EPI == 5) {
    const int kind = tn >> 10;  // 0=q, 1=k, 2=v
#pragma unroll
    for (int n = 0; n < 4; n++) {
      const int c = c0 + n * 16 + (lane & 15);
      const int hh = (c & 1023) >> 7, d = c & 127, jp = d >> 1;
      const float bsv = bias[c];
#pragma unroll
      for (int m = 0; m < 4; m++) {
        const int rb = r0 + m * 16 + ((lane >> 4) << 2);
#pragma unroll
        for (int j = 0; j < 4; j++) {
          const int r = rb + j;
          const float x = acc[m][n][j] + bsv;
          const float xo = __shfl_xor(x, 1);   // pair value (col ^ 1)
          const int b = r / T, t = r % T;
          if (kind == 2) {
            ((__bf16*)C)[2 * QSZ + ((size_t)((b * H + hh) * HD + d)) * T + t] =
                (__bf16)x;
          } else {
            const float cs = rct[t * 64 + jp], sn = rst[t * 64 + jp];
            const float o = (c & 1) ? (x * cs + xo * sn) : (x * cs - xo * sn);
            ((__bf16*)C)[(size_t)kind * QSZ +
                         ((size_t)((b * H + hh) * T + t)) * HD + d] = (__bf16)o;
          }
        }
      }
    }
    return;
  }
#pragma unroll
  for (int n = 0; n < 4; n++) {
    const int c = c0 + n * 16 + (lane & 15);
    if (c >= N) continue;
    const float bsv = (bias && (EPI != 4 || bz == 0)) ? bias[c] : 0.f;
#pragma unroll
    for (int m = 0; m < 4; m++) {
      const int rb = r0 + m * 16 + ((lane >> 4) << 2);
#pragma unroll
      for (int j = 0; j < 4; j++) {
        const int r = rb + j;
        if (r >= M) continue;
        float x = acc[m][n][j] + bsv;
        if constexpr (EPI == 4) {
          atomicAdd((float*)C + (size_t)r * ldC + c, x);
        } else {
          const size_t idx = (size_t)bz * sC + (size_t)r * ldC + c;
          if constexpr (EPI == 2) {
            const float u = x;
            const float gl =
                0.5f * u * (1.f + tanhf(0.7978845608f * (u + 0.044715f * u * u * u)));
            ((__bf16*)C)[idx] = (__bf16)gl;
          } else {
            ((float*)C)[idx] += x;
          }
        }
      }
    }
  }
}

// ---------------------------------------------------------------------------
// Fused attention: one block per (b,h). 4 waves x 48 Q-rows.
// LDS: K [192][128] swz (48KB, phase 1, overlaid by P later);
//      P [192][192] swz (73.7KB); V^T 3 x [128][64] swz (48KB). dyn 122880B.
// ---------------------------------------------------------------------------
__global__ __launch_bounds__(256) void k_attn(const __bf16* __restrict__ qb,
                                              const __bf16* __restrict__ kb,
                                              const __bf16* __restrict__ vT,
                                              __bf16* __restrict__ ob) {
  extern __shared__ char smem[];
  __bf16* Kl = (__bf16*)smem;             // [192][128]
  __bf16* Pl = (__bf16*)smem;             // [192][192] (after barrier)
  __bf16* Vl = (__bf16*)(smem + 73728);   // 3 x [128][64]
  const int bh = blockIdx.x;
  const int tid = threadIdx.x, lane = tid & 63, wv = tid >> 6;
  const int g4 = lane >> 4, l15 = lane & 15;
  const size_t hoff = (size_t)bh * T * HD;
  const size_t voff = (size_t)bh * HD * T;

  // --- hoist Q fragments (regs) ---
  bf16x8 qf[3][4];
#pragma unroll
  for (int m = 0; m < 3; m++)
#pragma unroll
    for (int ks = 0; ks < 4; ks++) {
      const int tq = wv * 48 + m * 16 + l15;
      qf[m][ks] = *(const bf16x8*)(qb + hoff + (size_t)tq * HD + ks * 32 + g4 * 8);
    }

  // --- stage K: 48 chunks of 4 rows x 16 slots(16B), swizzled source ---
#pragma unroll
  for (int ci = 0; ci < 12; ci++) {
    const int ch = wv * 12 + ci;
    const int grow = ch * 4 + g4;
    const int sl = l15 ^ (grow & 7);
    gload16(kb + hoff + (size_t)grow * HD + sl * 8, Kl + ch * 512);
  }
  // --- stage V^T: 3 subtiles x 16 chunks of 8 rows x 8 slots ---
#pragma unroll
  for (int ci = 0; ci < 12; ci++) {
    const int ch = wv * 12 + ci;
    const int c = ch >> 4, ch2 = ch & 15;
    const int d = ch2 * 8 + (lane >> 3);
    const int sl = (lane & 7) ^ (d & 7);
    gload16(vT + voff + (size_t)d * T + c * 64 + sl * 8,
            Vl + c * 8192 + ch2 * 512);
  }
  asm volatile("s_waitcnt vmcnt(0)" ::: "memory");
  __builtin_amdgcn_s_barrier();

  // --- S = Q K^T ---
  f32x4 sacc[3][12];
#pragma unroll
  for (int m = 0; m < 3; m++)
#pragma unroll
    for (int nf = 0; nf < 12; nf++) sacc[m][nf] = (f32x4)(0.f);
#pragma unroll
  for (int ks = 0; ks < 4; ks++)
#pragma unroll
    for (int nf = 0; nf < 12; nf++) {
      const int row = nf * 16 + l15;
      const int sl = (ks * 4 + g4) ^ (row & 7);
      const bf16x8 kf = *(const bf16x8*)&Kl[row * 128 + sl * 8];
#pragma unroll
      for (int m = 0; m < 3; m++)
        sacc[m][nf] = __builtin_amdgcn_mfma_f32_16x16x32_bf16(qf[m][ks], kf,
                                                              sacc[m][nf], 0, 0, 0);
    }

  // --- softmax (scale, causal mask, in-reg row reduce) ---
  const float scale = 0.08838834764831845f;
  float inv[3][4];
#pragma unroll
  for (int m = 0; m < 3; m++)
#pragma unroll
    for (int j = 0; j < 4; j++) {
      const int tq = wv * 48 + m * 16 + g4 * 4 + j;
#pragma unroll
      for (int nf = 0; nf < 12; nf++) {
        const int c = nf * 16 + l15;
        float v = sacc[m][nf][j] * scale;
        if (tq < S && c > tq) v = -1e30f;
        sacc[m][nf][j] = v;
      }
      float mm = -1e30f;
#pragma unroll
      for (int nf = 0; nf < 12; nf++) mm = fmaxf(mm, sacc[m][nf][j]);
#pragma unroll
      for (int o = 1; o < 16; o <<= 1) mm = fmaxf(mm, __shfl_xor(mm, o));
      float sum = 0.f;
#pragma unroll
      for (int nf = 0; nf < 12; nf++) {
        const float e = __expf(sacc[m][nf][j] - mm);
        sacc[m][nf][j] = e;
        sum += e;
      }
#pragma unroll
      for (int o = 1; o < 16; o <<= 1) sum += __shfl_xor(sum, o);
      inv[m][j] = 1.f / sum;
    }

  // --- P to LDS (overlays K; all waves' K reads complete first) ---
  __builtin_amdgcn_s_barrier();
#pragma unroll
  for (int m = 0; m < 3; m++)
#pragma unroll
    for (int nf = 0; nf < 12; nf++)
#pragma unroll
      for (int j = 0; j < 4; j++) {
        const int q = wv * 48 + m * 16 + g4 * 4 + j;
        const int c = nf * 16 + l15;
        Pl[q * 192 + (((c >> 3) ^ (q & 7)) * 8) + (c & 7)] =
            (__bf16)(sacc[m][nf][j] * inv[m][j]);
      }
  asm volatile("s_waitcnt lgkmcnt(0)" ::: "memory");
  __builtin_amdgcn_sched_barrier(0);

  // --- O = P V (wave-local P rows) ---
  f32x4 oacc[3][8];
#pragma unroll
  for (int m = 0; m < 3; m++)
#pragma unroll
    for (int nf = 0; nf < 8; nf++) oacc[m][nf] = (f32x4)(0.f);
#pragma unroll
  for (int ks = 0; ks < 6; ks++) {
    bf16x8 pf[3];
#pragma unroll
    for (int m = 0; m < 3; m++) {
      const int q = wv * 48 + m * 16 + l15;
      const int sl = (ks * 4 + g4) ^ (q & 7);
      pf[m] = *(const bf16x8*)&Pl[q * 192 + sl * 8];
    }
#pragma unroll
    for (int nf = 0; nf < 8; nf++) {
      const int d = nf * 16 + l15;
      const int sl = ((ks & 1) * 4 + g4) ^ (d & 7);
      const bf16x8 vf = *(const bf16x8*)&Vl[(ks >> 1) * 8192 + d * 64 + sl * 8];
#pragma unroll
      for (int m = 0; m < 3; m++)
        oacc[m][nf] = __builtin_amdgcn_mfma_f32_16x16x32_bf16(pf[m], vf,
                                                              oacc[m][nf], 0, 0, 0);
    }
  }

  // --- write O into packed ob layout ---
  const int b = bh >> 3, hh = bh & 7;
#pragma unroll
  for (int m = 0; m < 3; m++)
#pragma unroll
    for (int nf = 0; nf < 8; nf++) {
      const int d = nf * 16 + l15;
#pragma unroll
      for (int j = 0; j < 4; j++) {
        const int tq = wv * 48 + m * 16 + g4 * 4 + j;
        ob[((size_t)(b * T + tq)) * D + hh * HD + d] = (__bf16)oacc[m][nf][j];
      }
    }
}

// ---------------------------------------------------------------------------
// Decoder GEMM: logits[MD,V] = zb[MD,D] * DecT[V,D]^T + db.
// 256x256x64 tile, 512 thr / 8 waves (2Mx4N), 128KB dynamic LDS, 2-buffer
// counted-vmcnt(8), 2 MFMA sub-phases per K-tile; XCD-chunked M-fastest
// swizzle; 4-pass LDS-staged f32 epilogue (full 128B lines).
// ---------------------------------------------------------------------------
static constexpr int DEC_NT = (V + 255) / 256;        // 392
static constexpr int DEC_NWG = 8 * DEC_NT;            // 3136 (div by 8)

__global__ __launch_bounds__(512, 2) void k_dec(const __bf16* __restrict__ A,
                                                const __bf16* __restrict__ Bt,
                                                const float* __restrict__ bias,
                                                float* __restrict__ C) {
  extern __shared__ char smem[];
  __bf16* lds = (__bf16*)smem;         // 65536 bf16 = 128 KB
  float* cbuf = (float*)smem;          // epilogue alias: 64 x 256 f32 (64 KB)

  const int bid = blockIdx.x;
  const int swz = (bid & 7) * DEC_NT + (bid >> 3);
  const int tm = (swz & 7) * 256, tn = (swz >> 3) * 256;
  const int tid = threadIdx.x;
  const int lane = tid & 63, wv = tid >> 6;
  const int wm = wv >> 2, wn = wv & 3;         // 2x4 wave grid, 128x64 each
  const int g4 = lane >> 4, l15 = lane & 15;

  f32x4 acc[8][4];
#pragma unroll
  for (int m = 0; m < 8; m++)
#pragma unroll
    for (int n = 0; n < 4; n++) acc[m][n] = (f32x4)(0.f);

  // staging: round i: local row = (tid>>3)+i*64, phys 16B-slot = tid&7,
  // logical k-slot = (tid&7)^(row&7) -> pre-swizzled global k offset.
  const int srow = tid >> 3;                          // 0..63
  const int lcol = (((tid & 7) ^ (srow & 7)) * 8);    // bf16 elems
  int arows[4], brows[4];
#pragma unroll
  for (int i = 0; i < 4; i++) {
    arows[i] = tm + i * 64 + srow;                    // M=2048, in range
    int br = tn + i * 64 + srow; if (br > V - 1) br = V - 1;
    brows[i] = br;
  }

  auto stage = [&](int buf, int kk) {
    __bf16* Abuf = lds + buf * 32768;
    __bf16* Bbuf = lds + 16384 + buf * 32768;
#pragma unroll
    for (int i = 0; i < 4; i++)
      gload16(A + (size_t)arows[i] * D + kk + lcol, Abuf + i * 4096 + (size_t)tid * 8);
#pragma unroll
    for (int i = 0; i < 4; i++)
      gload16(Bt + (size_t)brows[i] * D + kk + lcol, Bbuf + i * 4096 + (size_t)tid * 8);
  };

  // compute one K-tile (64 wide): 2 sub-phases (ks=0,1), 32 MFMA each.
  auto compute = [&](int cur) {
    const __bf16* Abuf = lds + cur * 32768;
    const __bf16* Bbuf = lds + 16384 + cur * 32768;
    bf16x8 af[8], bfv[4];
    // --- ks = 0 ---
#pragma unroll
    for (int m = 0; m < 8; m++) {
      const int row = wm * 128 + m * 16 + l15;
      af[m] = *(const bf16x8*)&Abuf[row * 64 + (g4 ^ (row & 7)) * 8];
    }
#pragma unroll
    for (int n = 0; n < 4; n++) {
      const int row = wn * 64 + n * 16 + l15;
      bfv[n] = *(const bf16x8*)&Bbuf[row * 64 + (g4 ^ (row & 7)) * 8];
    }
    asm volatile("s_waitcnt lgkmcnt(0)" ::: "memory");
    __builtin_amdgcn_sched_barrier(0);
#pragma unroll
    for (int m = 0; m < 8; m++)
#pragma unroll
      for (int n = 0; n < 4; n++)
        acc[m][n] = __builtin_amdgcn_mfma_f32_16x16x32_bf16(af[m], bfv[n],
                                                            acc[m][n], 0, 0, 0);
    // --- ks = 1 ---
#pragma unroll
    for (int m = 0; m < 8; m++) {
      const int row = wm * 128 + m * 16 + l15;
      af[m] = *(const bf16x8*)&Abuf[row * 64 + ((4 + g4) ^ (row & 7)) * 8];
    }
#pragma unroll
    for (int n = 0; n < 4; n++) {
      const int row = wn * 64 + n * 16 + l15;
      bfv[n] = *(const bf16x8*)&Bbuf[row * 64 + ((4 + g4) ^ (row & 7)) * 8];
    }
    asm volatile("s_waitcnt lgkmcnt(0)" ::: "memory");
    __builtin_amdgcn_sched_barrier(0);
    __builtin_amdgcn_s_barrier();   // all waves done reading buf[cur]
#pragma unroll
    for (int m = 0; m < 8; m++)
#pragma unroll
      for (int n = 0; n < 4; n++)
        acc[m][n] = __builtin_amdgcn_mfma_f32_16x16x32_bf16(af[m], bfv[n],
                                                            acc[m][n], 0, 0, 0);
  };

  const int NT = D / 64;           // 16 K-tiles
  stage(0, 0);
  for (int it = 0; it < NT - 1; ++it) {
    const int cur = it & 1;
    stage(cur ^ 1, (it + 1) << 6);                    // 8 loads in flight
    asm volatile("s_waitcnt vmcnt(8)" ::: "memory");  // tile-cur loads landed
    __builtin_amdgcn_s_barrier();
    compute(cur);
  }
  asm volatile("s_waitcnt vmcnt(0)" ::: "memory");
  __builtin_amdgcn_s_barrier();
  compute((NT - 1) & 1);
  __syncthreads();   // all waves past compute barrier; cbuf aliasing safe

  // --- LDS-staged epilogue: 4 passes of 64 rows x 256 cols, full-line stores
  const bool full = (tn + 256 <= V);
  for (int pass = 0; pass < 4; ++pass) {
    if (pass) __syncthreads();           // prior pass reads done
    if (wm == (pass >> 1)) {
      const int mfb = (pass & 1) * 4;
#pragma unroll
      for (int n = 0; n < 4; n++) {
        const int col = wn * 64 + n * 16 + l15;
        const float bsv = (tn + col < V) ? bias[tn + col] : 0.f;
#pragma unroll
        for (int m2 = 0; m2 < 4; m2++) {
#pragma unroll
          for (int j = 0; j < 4; j++) {
            const int row = m2 * 16 + g4 * 4 + j;           // 0..63 in pass
            const int phys = (col >> 2) ^ (row & 7);        // 16B-slot swz
            cbuf[row * 256 + phys * 4 + (col & 3)] = acc[mfb + m2][n][j] + bsv;
          }
        }
      }
    }
    __syncthreads();
    const int rbase = tm + pass * 64;
    if (full) {
      const int row = tid >> 3, c8 = tid & 7;               // 64 rows x 8 lanes
#pragma unroll
      for (int i = 0; i < 8; ++i) {
        const int ps = (c8 ^ (row & 7)) + i * 8;            // phys slot
        const f32x4 v = *(const f32x4*)&cbuf[row * 256 + ps * 4];
        *(f32x4*)&C[(size_t)(rbase + row) * V + tn + (c8 + i * 8) * 4] = v;
      }
    } else {
      for (int idx = tid; idx < 64 * 256; idx += 512) {
        const int row = idx >> 8, col = idx & 255;
        if (tn + col < V)
          C[(size_t)(rbase + row) * V + tn + col] =
              cbuf[row * 256 + (((col >> 2) ^ (row & 7)) << 2) + (col & 3)];
      }
    }
  }
}

// ---------------------------------------------------------------------------
// transpose-cast: in f32 (R,C) -> out bf16 (C,R); vectorized bf16x4 stores.
// ---------------------------------------------------------------------------
__global__ __launch_bounds__(256) void k_transpose(const float* __restrict__ in,
                                                   __bf16* __restrict__ out,
                                                   int R, int C) {
  __shared__ __bf16 tile[32][33];
  const int c0 = blockIdx.x * 32, r0 = blockIdx.y * 32;
  const int tx = threadIdx.x & 31, ty = threadIdx.x >> 5;  // 32x8
#pragma unroll
  for (int i = 0; i < 32; i += 8) {
    const int r = r0 + ty + i, c = c0 + tx;
    tile[ty + i][tx] = (r < R && c < C) ? (__bf16)in[(size_t)r * C + c] : (__bf16)0.f;
  }
  __syncthreads();
  const int oc = threadIdx.x >> 3, rch = (threadIdx.x & 7) * 4;
  const int occ = c0 + oc, orr = r0 + rch;
  if (occ < C && orr + 3 < R) {
    bf16x4 v;
#pragma unroll
    for (int j = 0; j < 4; j++) v[j] = tile[rch + j][oc];
    *(bf16x4*)(out + (size_t)occ * R + orr) = v;
  }
}

// batched (1024,1024) transpose-cast: z selects {wq,wk,wv,wo}; first three
// go to WqkvT slabs, wo to WoT.
__global__ __launch_bounds__(256) void k_transpose4(const float* __restrict__ s0,
                                                    const float* __restrict__ s1,
                                                    const float* __restrict__ s2,
                                                    const float* __restrict__ s3,
                                                    __bf16* __restrict__ dqkv,
                                                    __bf16* __restrict__ dwo) {
  __shared__ __bf16 tile[32][33];
  const int zz = blockIdx.z;
  const float* in = (zz == 0) ? s0 : (zz == 1) ? s1 : (zz == 2) ? s2 : s3;
  __bf16* out = (zz == 3) ? dwo : dqkv + (size_t)zz * D * D;
  const int c0 = blockIdx.x * 32, r0 = blockIdx.y * 32;
  const int tx = threadIdx.x & 31, ty = threadIdx.x >> 5;  // 32x8
#pragma unroll
  for (int i = 0; i < 32; i += 8)
    tile[ty + i][tx] = (__bf16)in[(size_t)(r0 + ty + i) * D + c0 + tx];
  __syncthreads();
  const int oc = threadIdx.x >> 3, rch = (threadIdx.x & 7) * 4;
  bf16x4 v;
#pragma unroll
  for (int j = 0; j < 4; j++) v[j] = tile[rch + j][oc];
  *(bf16x4*)(out + (size_t)(c0 + oc) * D + r0 + rch) = v;
}

__global__ __launch_bounds__(256) void k_concat_bias(const float* bq,
                                                     const float* bk,
                                                     const float* bv,
                                                     float* out) {
  const int i = blockIdx.x * 256 + threadIdx.x;
  if (i < D) { out[i] = bq[i]; out[D + i] = bk[i]; out[2 * D + i] = bv[i]; }
}

__global__ __launch_bounds__(256) void k_rope_table(float* __restrict__ ct,
                                                    float* __restrict__ st) {
  const int i = blockIdx.x * 256 + threadIdx.x;
  if (i < T * 64) {
    const int t = i >> 6, j = i & 63;
    const float inv = expf(-((float)(2 * j) * (1.f / 128.f)) * 9.210340371976184f);
    const float ang = (float)t * inv;
    ct[i] = cosf(ang);
    st[i] = sinf(ang);
  }
}

__global__ __launch_bounds__(256) void k_build_z(const int* __restrict__ tokens,
                                                 const float* __restrict__ embed,
                                                 const float* __restrict__ scratch,
                                                 float* __restrict__ z) {
  const int row = blockIdx.x;  // b*T + t
  const int b = row / T, t = row % T;
  const float* src = (t < S) ? embed + (size_t)tokens[b * S + t] * D
                             : scratch + (size_t)(t - S) * D;
  ((float4*)(z + (size_t)row * D))[threadIdx.x] =
      ((const float4*)src)[threadIdx.x];
}

// z (+= te), h = LN(z)*s + b  (bf16 out)
template <bool ADDT>
__global__ __launch_bounds__(256) void k_ln(float* __restrict__ z,
                                            const float* __restrict__ te,
                                            const float* __restrict__ gs,
                                            const float* __restrict__ gb,
                                            __bf16* __restrict__ h) {
  const int row = blockIdx.x, tid = threadIdx.x;
  float* zp = z + (size_t)row * D;
  float4 x = ((float4*)zp)[tid];
  if (ADDT) {
    const float4 t4 = ((const float4*)te)[tid];
    x.x += t4.x; x.y += t4.y; x.z += t4.z; x.w += t4.w;
    ((float4*)zp)[tid] = x;
  }
  float s = x.x + x.y + x.z + x.w;
  float s2 = x.x * x.x + x.y * x.y + x.z * x.z + x.w * x.w;
#pragma unroll
  for (int o = 32; o; o >>= 1) { s += __shfl_xor(s, o); s2 += __shfl_xor(s2, o); }
  __shared__ float rs[4], rq[4];
  const int wv = tid >> 6, ln = tid & 63;
  if (!ln) { rs[wv] = s; rq[wv] = s2; }
  __syncthreads();
  s = rs[0] + rs[1] + rs[2] + rs[3];
  s2 = rq[0] + rq[1] + rq[2] + rq[3];
  const float mu = s * (1.f / D);
  const float var = s2 * (1.f / D) - mu * mu;
  const float rinv = 1.0f / sqrtf(var + 1e-6f);
  const int c = tid * 4;
  const float4 g4 = ((const float4*)gs)[tid];
  const float4 b4 = ((const float4*)gb)[tid];
  bf16x4 o4;
  o4[0] = (__bf16)((x.x - mu) * rinv * g4.x + b4.x);
  o4[1] = (__bf16)((x.y - mu) * rinv * g4.y + b4.y);
  o4[2] = (__bf16)((x.z - mu) * rinv * g4.z + b4.z);
  o4[3] = (__bf16)((x.w - mu) * rinv * g4.w + b4.w);
  *(bf16x4*)(h + (size_t)row * D + c) = o4;
}

__global__ __launch_bounds__(256) void k_halt(const float* __restrict__ z,
                                              const float* __restrict__ hw,
                                              const float* __restrict__ hb,
                                              float* __restrict__ out) {
  const int b = blockIdx.x, tid = threadIdx.x;
  const float4 w4 = ((const float4*)hw)[tid];
  float acc = 0.f;
  for (int j = 0; j < SCR; j++) {
    const float4 x = ((const float4*)(z + ((size_t)(b * T + S + j)) * D))[tid];
    acc += x.x * w4.x + x.y * w4.y + x.z * w4.z + x.w * w4.w;
  }
#pragma unroll
  for (int o = 32; o; o >>= 1) acc += __shfl_xor(acc, o);
  __shared__ float rs[4];
  const int wv = tid >> 6, ln = tid & 63;
  if (!ln) rs[wv] = acc;
  __syncthreads();
  if (tid == 0) {
    const float tot = rs[0] + rs[1] + rs[2] + rs[3];
    out[b] = 1.f / (1.f + expf(-(tot * (1.f / SCR) + hb[0])));
  }
}

// compact cast: zb[b*S+s] = bf16(z[b*T+s]), only token rows
__global__ __launch_bounds__(256) void k_cast(const float* __restrict__ z,
                                              __bf16* __restrict__ zb) {
  const int row = blockIdx.x;            // b*S + s
  const int b = row >> 7, s = row & 127; // S = 128
  const float4 x = ((const float4*)(z + ((size_t)(b * T + s)) * D))[threadIdx.x];
  bf16x4 o;
  o[0] = (__bf16)x.x; o[1] = (__bf16)x.y; o[2] = (__bf16)x.z; o[3] = (__bf16)x.w;
  *(bf16x4*)(zb + (size_t)row * D + threadIdx.x * 4) = o;
}

// ---------------------------------------------------------------------------
extern "C" void kernel_launch(void* const* d_in, const int* in_sizes, int n_in,
                              void* d_out, int out_size, void* d_ws,
                              size_t ws_size, hipStream_t stream) {
  const int* tokens = (const int*)d_in[0];
  const float* embed = (const float*)d_in[1];
  const float* time_embed = (const float*)d_in[2];
  const float* scratch = (const float*)d_in[3];
  const float* wq = (const float*)d_in[4];  const float* bq = (const float*)d_in[5];
  const float* wk = (const float*)d_in[6];  const float* bk = (const float*)d_in[7];
  const float* wvv = (const float*)d_in[8]; const float* bv = (const float*)d_in[9];
  const float* wo = (const float*)d_in[10]; const float* bo = (const float*)d_in[11];
  const float* ln1s = (const float*)d_in[12]; const float* ln1b = (const float*)d_in[13];
  const float* ln2s = (const float*)d_in[14]; const float* ln2b = (const float*)d_in[15];
  const float* w1 = (const float*)d_in[16]; const float* b1 = (const float*)d_in[17];
  const float* w2 = (const float*)d_in[18]; const float* b2 = (const float*)d_in[19];
  const float* hw = (const float*)d_in[20]; const float* hb = (const float*)d_in[21];
  const float* dw = (const float*)d_in[22]; const float* db = (const float*)d_in[23];

  char* w = (char*)d_ws;
  size_t off = 0;
  auto al = [&](size_t n) { size_t o = off; off += (n + 255) & ~(size_t)255; return o; };
  const size_t oWqkvT = al((size_t)3 * D * D * 2);
  const size_t oWoT   = al((size_t)D * D * 2);
  const size_t oW1T   = al((size_t)DFF * D * 2);
  const size_t oW2T   = al((size_t)D * DFF * 2);
  const size_t oDecT  = al((size_t)V * D * 2);
  const size_t oBqkv  = al((size_t)3 * D * 4);
  const size_t oCt    = al((size_t)T * 64 * 4);
  const size_t oSt    = al((size_t)T * 64 * 4);
  const size_t oZ     = al((size_t)ROWS * D * 4);
  const size_t oH     = al((size_t)ROWS * D * 2);   // h; later zb alias
  const size_t oG     = al((size_t)ROWS * DFF * 2); // gelu out (bf16)
  const size_t oOB    = al((size_t)ROWS * D * 2);   // attn out packed (bf16)
  const size_t oQ     = al(QSZ * 2);
  const size_t oK     = al(QSZ * 2);
  const size_t oVT    = al(QSZ * 2);
  (void)ws_size; (void)in_sizes; (void)n_in; (void)out_size;

  __bf16* WqkvT = (__bf16*)(w + oWqkvT);
  __bf16* WoT   = (__bf16*)(w + oWoT);
  __bf16* W1T   = (__bf16*)(w + oW1T);
  __bf16* W2T   = (__bf16*)(w + oW2T);
  __bf16* DecT  = (__bf16*)(w + oDecT);
  float*  bqkv  = (float*)(w + oBqkv);
  float*  ct    = (float*)(w + oCt);
  float*  st    = (float*)(w + oSt);
  float*  z     = (float*)(w + oZ);
  __bf16* h     = (__bf16*)(w + oH);
  __bf16* g     = (__bf16*)(w + oG);
  __bf16* ob    = (__bf16*)(w + oOB);
  __bf16* qb    = (__bf16*)(w + oQ);    // qb|kb|vT contiguous (EPI=5 relies on QSZ offsets)
  __bf16* kb    = (__bf16*)(w + oK);
  __bf16* vT    = (__bf16*)(w + oVT);
  __bf16* zb    = (__bf16*)(w + oH);    // alias (h dead at decode time)

  float* logits = (float*)d_out;
  float* halts  = (float*)d_out + LOGITS;

  // --- weight prep (runs every call; deterministic) ---
  k_transpose4<<<dim3(32, 32, 4), 256, 0, stream>>>(wq, wk, wvv, wo, WqkvT, WoT);
  k_transpose<<<dim3(128, 32), 256, 0, stream>>>(w1, W1T, D, DFF);
  k_transpose<<<dim3(32, 128), 256, 0, stream>>>(w2, W2T, DFF, D);
  k_transpose<<<dim3((V + 31) / 32, 32), 256, 0, stream>>>(dw, DecT, D, V);
  k_concat_bias<<<4, 256, 0, stream>>>(bq, bk, bv, bqkv);
  k_rope_table<<<(T * 64 + 255) / 256, 256, 0, stream>>>(ct, st);
  k_build_z<<<ROWS, 256, 0, stream>>>(tokens, embed, scratch, z);

  for (int step = 0; step < NSTEP; step++) {
    k_ln<true><<<ROWS, 256, 0, stream>>>(z, time_embed + (size_t)step * D, ln1s, ln1b, h);
    // QKV (3072,1024)x(1024,3072) + rope fused -> qb/kb/vT directly
    k_gemm<5><<<dim3(24, 24, 1), 256, 65536, stream>>>(h, 0, D, ROWS, WqkvT, 0, D,
                                                       3 * D, D, bqkv, qb, 0, 0, ct, st);
    // fused attention: scores + softmax + PV -> ob
    k_attn<<<BB * H, 256, 122880, stream>>>(qb, kb, vT, ob);
    // WO + residual into z
    k_gemm<1><<<dim3(8, 24, 1), 256, 65536, stream>>>(ob, 0, D, ROWS, WoT, 0, D, D,
                                                      D, bo, z, 0, D, nullptr, nullptr);
    k_ln<false><<<ROWS, 256, 0, stream>>>(z, nullptr, ln2s, ln2b, h);
    // MLP1 + gelu -> bf16
    k_gemm<2><<<dim3(32, 24, 1), 256, 65536, stream>>>(h, 0, D, ROWS, W1T, 0, D,
                                                       DFF, D, b1, g, 0, DFF, nullptr, nullptr);
    // MLP2 + residual into z: split-K=4 (chunks of 1024), atomicAdd epilogue
    k_gemm<4><<<dim3(8, 24, 4), 256, 65536, stream>>>(g, 0, DFF, ROWS, W2T, 0, DFF,
                                                      D, DFF / 4, b2, z, 0, D, nullptr, nullptr);
    k_halt<<<BB, 256, 0, stream>>>(z, hw, hb, halts + step * BB);
  }

  // decoder: one merged (2048,1024) x (1024,100277) GEMM, 256x256x64 tiles
  k_cast<<<MD, 256, 0, stream>>>(z, zb);
  k_dec<<<DEC_NWG, 512, 131072, stream>>>(zb, DecT, db, logits);
}

// Round 17
// 2710.257 us; speedup vs baseline: 1.0599x; 1.0599x over previous
//
#include <hip/hip_runtime.h>
#include <hip/hip_bf16.h>
#include <math.h>

// ---------------------------------------------------------------------------
// UniversalReasoner: 8-step recurrent transformer + vocab decoder, MI355X.
// Round 17:
//   - k_gemm reverted to R15 (R16's 24-read pre-issue cost VGPRs > it saved).
//   - k_attn: 2 blocks per (b,h) (Q split in halves) -> 256 blocks x 128 thr,
//     96KB LDS. Fixes the idle-CU bug (128 blocks @122KB = 1 blk/CU left
//     half the chip idle). Per-wave work unchanged (2 waves x 48 Q-rows);
//     q0=96 is 0 mod 8 so all (q&7) swizzles are local-coordinate safe.
//   - everything else identical to R15.
// ---------------------------------------------------------------------------

typedef float  f32x4  __attribute__((ext_vector_type(4)));
typedef __bf16 bf16x8 __attribute__((ext_vector_type(8)));
typedef __bf16 bf16x4 __attribute__((ext_vector_type(4)));

static constexpr int BB   = 16;     // batch
static constexpr int S    = 128;    // sequence tokens
static constexpr int SCR  = 64;     // scratch tokens
static constexpr int T    = 192;    // S + SCR
static constexpr int D    = 1024;
static constexpr int H    = 8;
static constexpr int HD   = 128;
static constexpr int DFF  = 4096;
static constexpr int NSTEP= 8;
static constexpr int V    = 100277;
static constexpr int ROWS = BB * T; // 3072
static constexpr int MD   = BB * S; // 2048 decoder rows
static constexpr long long LOGITS = (long long)BB * S * V; // 205367296
static constexpr size_t QSZ = (size_t)BB * H * T * HD;     // per q/k/v tensor

#define DEV __device__ __forceinline__

DEV void gload16(const __bf16* g, __bf16* l) {
  __builtin_amdgcn_global_load_lds(
      (__attribute__((address_space(1))) void*)(g),
      (__attribute__((address_space(3))) void*)(l), 16, 0, 0);
}

// ---------------------------------------------------------------------------
// Workhorse GEMM (128x128x64):  C[M,N] = A[M,K] * Bt[N,K]^T (+epilogue)
// EPI: 1 = bias + in-place f32 residual add ; 2 = bias + gelu -> bf16 ;
//      4 = split-K: bz = k-chunk, atomicAdd into f32 C, bias only on bz==0 ;
//      5 = QKV+rope: writes q/k bf16 (rope'd) and vT bf16 via kind = tn>>10.
// Requires K % 64 == 0. Launch with 65536 B dynamic LDS.
// ---------------------------------------------------------------------------
template <int EPI>
__global__ __launch_bounds__(256) void k_gemm(
    const __bf16* __restrict__ A, long long sA, int ldA, int M,
    const __bf16* __restrict__ Bt, long long sB, int ldB, int N, int K,
    const float* __restrict__ bias, void* __restrict__ C, long long sC,
    int ldC, const float* __restrict__ rct, const float* __restrict__ rst) {
  extern __shared__ char smem[];
  __bf16* lds = (__bf16*)smem;   // A(buf)=lds+buf*16384; B(buf)=+8192

  const int bz = blockIdx.z;
  const __bf16* Ab;
  const __bf16* Bb;
  if constexpr (EPI == 4) {
    Ab = A + (size_t)bz * K;   // k-chunk offset within row
    Bb = Bt + (size_t)bz * K;
  } else {
    Ab = A + (size_t)bz * sA;
    Bb = Bt + (size_t)bz * sB;
  }
  const int tm = blockIdx.y * 128, tn = blockIdx.x * 128;
  const int tid = threadIdx.x;
  const int lane = tid & 63, wv = tid >> 6;
  const int wr = wv >> 1, wc = wv & 1;  // 2x2 wave grid, 64x64 per wave
  const int g4 = lane >> 4, l15 = lane & 15;

  f32x4 acc[4][4];
#pragma unroll
  for (int m = 0; m < 4; m++)
#pragma unroll
    for (int n = 0; n < 4; n++) acc[m][n] = (f32x4)(0.f);

  // staging: chunk = i*256+tid -> local row = i*32 + (tid>>3), phys slot tid&7
  const int srow = tid >> 3;                          // 0..31
  const int lcol = (((tid & 7) ^ (srow & 7)) * 8);    // pre-swizzled k offset
  int arows[4], brows[4];
#pragma unroll
  for (int i = 0; i < 4; i++) {
    int ar = tm + i * 32 + srow; if (ar > M - 1) ar = M - 1;
    int br = tn + i * 32 + srow; if (br > N - 1) br = N - 1;
    arows[i] = ar; brows[i] = br;
  }

  auto stage = [&](int buf, int kk) {
    __bf16* Abuf = lds + buf * 16384;
    __bf16* Bbuf = lds + 8192 + buf * 16384;
#pragma unroll
    for (int i = 0; i < 4; i++)
      gload16(Ab + (size_t)arows[i] * ldA + kk + lcol, Abuf + i * 2048 + (size_t)tid * 8);
#pragma unroll
    for (int i = 0; i < 4; i++)
      gload16(Bb + (size_t)brows[i] * ldB + kk + lcol, Bbuf + i * 2048 + (size_t)tid * 8);
  };

  // one K-tile (64 wide): 2 sub-phases, 16 MFMA each (32 per wave).
  auto compute = [&](int cur) {
    const __bf16* Abuf = lds + cur * 16384;
    const __bf16* Bbuf = lds + 8192 + cur * 16384;
    bf16x8 af[4], bfv[4];
    // --- ks = 0 ---
#pragma unroll
    for (int m = 0; m < 4; m++) {
      const int row = wr * 64 + m * 16 + l15;
      af[m] = *(const bf16x8*)&Abuf[row * 64 + (g4 ^ (row & 7)) * 8];
    }
#pragma unroll
    for (int n = 0; n < 4; n++) {
      const int row = wc * 64 + n * 16 + l15;
      bfv[n] = *(const bf16x8*)&Bbuf[row * 64 + (g4 ^ (row & 7)) * 8];
    }
    asm volatile("s_waitcnt lgkmcnt(0)" ::: "memory");
    __builtin_amdgcn_sched_barrier(0);
#pragma unroll
    for (int m = 0; m < 4; m++)
#pragma unroll
      for (int n = 0; n < 4; n++)
        acc[m][n] = __builtin_amdgcn_mfma_f32_16x16x32_bf16(af[m], bfv[n],
                                                            acc[m][n], 0, 0, 0);
    // --- ks = 1 ---
#pragma unroll
    for (int m = 0; m < 4; m++) {
      const int row = wr * 64 + m * 16 + l15;
      af[m] = *(const bf16x8*)&Abuf[row * 64 + ((4 + g4) ^ (row & 7)) * 8];
    }
#pragma unroll
    for (int n = 0; n < 4; n++) {
      const int row = wc * 64 + n * 16 + l15;
      bfv[n] = *(const bf16x8*)&Bbuf[row * 64 + ((4 + g4) ^ (row & 7)) * 8];
    }
    asm volatile("s_waitcnt lgkmcnt(0)" ::: "memory");
    __builtin_amdgcn_sched_barrier(0);
    __builtin_amdgcn_s_barrier();   // all waves done reading buf[cur]
#pragma unroll
    for (int m = 0; m < 4; m++)
#pragma unroll
      for (int n = 0; n < 4; n++)
        acc[m][n] = __builtin_amdgcn_mfma_f32_16x16x32_bf16(af[m], bfv[n],
                                                            acc[m][n], 0, 0, 0);
  };

  const int NT = K >> 6;           // K-tiles of 64 (K % 64 == 0)
  stage(0, 0);
  for (int it = 0; it < NT - 1; ++it) {
    const int cur = it & 1;
    stage(cur ^ 1, (it + 1) << 6);                    // 8 loads in flight
    asm volatile("s_waitcnt vmcnt(8)" ::: "memory");  // tile-cur loads landed
    __builtin_amdgcn_s_barrier();
    compute(cur);
  }
  asm volatile("s_waitcnt vmcnt(0)" ::: "memory");
  __builtin_amdgcn_s_barrier();
  compute((NT - 1) & 1);

  // epilogue: C/D layout col=lane&15, row=(lane>>4)*4+reg
  const int r0 = tm + wr * 64, c0 = tn + wc * 64;
  if constexpr (EPI == 5) {
    const int kind = tn >> 10;  // 0=q, 1=k, 2=v
#pragma unroll
    for (int n = 0; n < 4; n++) {
      const int c = c0 + n * 16 + (lane & 15);
      const int hh = (c & 1023) >> 7, d = c & 127, jp = d >> 1;
      const float bsv = bias[c];
#pragma unroll
      for (int m = 0; m < 4; m++) {
        const int rb = r0 + m * 16 + ((lane >> 4) << 2);
#pragma unroll
        for (int j = 0; j < 4; j++) {
          const int r = rb + j;
          const float x = acc[m][n][j] + bsv;
          const float xo = __shfl_xor(x, 1);   // pair value (col ^ 1)
          const int b = r / T, t = r % T;
          if (kind == 2) {
            ((__bf16*)C)[2 * QSZ + ((size_t)((b * H + hh) * HD + d)) * T + t] =
                (__bf16)x;
          } else {
            const float cs = rct[t * 64 + jp], sn = rst[t * 64 + jp];
            const float o = (c & 1) ? (x * cs + xo * sn) : (x * cs - xo * sn);
            ((__bf16*)C)[(size_t)kind * QSZ +
                         ((size_t)((b * H + hh) * T + t)) * HD + d] = (__bf16)o;
          }
        }
      }
    }
    return;
  }
#pragma unroll
  for (int n = 0; n < 4; n++) {
    const int c = c0 + n * 16 + (lane & 15);
    if (c >= N) continue;
    const float bsv = (bias && (EPI != 4 || bz == 0)) ? bias[c] : 0.f;
#pragma unroll
    for (int m = 0; m < 4; m++) {
      const int rb = r0 + m * 16 + ((lane >> 4) << 2);
#pragma unroll
      for (int j = 0; j < 4; j++) {
        const int r = rb + j;
        if (r >= M) continue;
        float x = acc[m][n][j] + bsv;
        if constexpr (EPI == 4) {
          atomicAdd((float*)C + (size_t)r * ldC + c, x);
        } else {
          const size_t idx = (size_t)bz * sC + (size_t)r * ldC + c;
          if constexpr (EPI == 2) {
            const float u = x;
            const float gl =
                0.5f * u * (1.f + tanhf(0.7978845608f * (u + 0.044715f * u * u * u)));
            ((__bf16*)C)[idx] = (__bf16)gl;
          } else {
            ((float*)C)[idx] += x;
          }
        }
      }
    }
  }
}

// ---------------------------------------------------------------------------
// Fused attention: 2 blocks per (b,h) (Q-halves), 128 thr / 2 waves x 48 rows.
// LDS: K [192][128] swz (48KB, overlaid by P [96][192] after barrier);
//      V^T 3 x [128][64] swz at +49152. dyn 98304 B -> 1 block/CU, 256 CUs.
// ---------------------------------------------------------------------------
__global__ __launch_bounds__(128) void k_attn(const __bf16* __restrict__ qb,
                                              const __bf16* __restrict__ kb,
                                              const __bf16* __restrict__ vT,
                                              __bf16* __restrict__ ob) {
  extern __shared__ char smem[];
  __bf16* Kl = (__bf16*)smem;             // [192][128]
  __bf16* Pl = (__bf16*)smem;             // [96][192] (after barrier)
  __bf16* Vl = (__bf16*)(smem + 49152);   // 3 x [128][64]
  const int bid = blockIdx.x;
  const int bh = bid >> 1, q0 = (bid & 1) * 96;   // Q-half base (96 % 8 == 0)
  const int tid = threadIdx.x, lane = tid & 63, wv = tid >> 6;  // wv in {0,1}
  const int g4 = lane >> 4, l15 = lane & 15;
  const size_t hoff = (size_t)bh * T * HD;
  const size_t voff = (size_t)bh * HD * T;

  // --- hoist Q fragments (regs) ---
  bf16x8 qf[3][4];
#pragma unroll
  for (int m = 0; m < 3; m++)
#pragma unroll
    for (int ks = 0; ks < 4; ks++) {
      const int tq = q0 + wv * 48 + m * 16 + l15;
      qf[m][ks] = *(const bf16x8*)(qb + hoff + (size_t)tq * HD + ks * 32 + g4 * 8);
    }

  // --- stage K: 48 chunks (24/wave) of 4 rows x 16 slots(16B), swz source ---
#pragma unroll
  for (int ci = 0; ci < 24; ci++) {
    const int ch = wv * 24 + ci;
    const int grow = ch * 4 + g4;
    const int sl = l15 ^ (grow & 7);
    gload16(kb + hoff + (size_t)grow * HD + sl * 8, Kl + ch * 512);
  }
  // --- stage V^T: 3 subtiles x 16 chunks (24/wave) of 8 rows x 8 slots ---
#pragma unroll
  for (int ci = 0; ci < 24; ci++) {
    const int ch = wv * 24 + ci;
    const int c = ch >> 4, ch2 = ch & 15;
    const int d = ch2 * 8 + (lane >> 3);
    const int sl = (lane & 7) ^ (d & 7);
    gload16(vT + voff + (size_t)d * T + c * 64 + sl * 8,
            Vl + c * 8192 + ch2 * 512);
  }
  asm volatile("s_waitcnt vmcnt(0)" ::: "memory");
  __builtin_amdgcn_s_barrier();

  // --- S = Q K^T ---
  f32x4 sacc[3][12];
#pragma unroll
  for (int m = 0; m < 3; m++)
#pragma unroll
    for (int nf = 0; nf < 12; nf++) sacc[m][nf] = (f32x4)(0.f);
#pragma unroll
  for (int ks = 0; ks < 4; ks++)
#pragma unroll
    for (int nf = 0; nf < 12; nf++) {
      const int row = nf * 16 + l15;
      const int sl = (ks * 4 + g4) ^ (row & 7);
      const bf16x8 kf = *(const bf16x8*)&Kl[row * 128 + sl * 8];
#pragma unroll
      for (int m = 0; m < 3; m++)
        sacc[m][nf] = __builtin_amdgcn_mfma_f32_16x16x32_bf16(qf[m][ks], kf,
                                                              sacc[m][nf], 0, 0, 0);
    }

  // --- softmax (scale, causal mask, in-reg row reduce) ---
  const float scale = 0.08838834764831845f;
  float inv[3][4];
#pragma unroll
  for (int m = 0; m < 3; m++)
#pragma unroll
    for (int j = 0; j < 4; j++) {
      const int tq = q0 + wv * 48 + m * 16 + g4 * 4 + j;
#pragma unroll
      for (int nf = 0; nf < 12; nf++) {
        const int c = nf * 16 + l15;
        float v = sacc[m][nf][j] * scale;
        if (tq < S && c > tq) v = -1e30f;
        sacc[m][nf][j] = v;
      }
      float mm = -1e30f;
#pragma unroll
      for (int nf = 0; nf < 12; nf++) mm = fmaxf(mm, sacc[m][nf][j]);
#pragma unroll
      for (int o = 1; o < 16; o <<= 1) mm = fmaxf(mm, __shfl_xor(mm, o));
      float sum = 0.f;
#pragma unroll
      for (int nf = 0; nf < 12; nf++) {
        const float e = __expf(sacc[m][nf][j] - mm);
        sacc[m][nf][j] = e;
        sum += e;
      }
#pragma unroll
      for (int o = 1; o < 16; o <<= 1) sum += __shfl_xor(sum, o);
      inv[m][j] = 1.f / sum;
    }

  // --- P to LDS (overlays K; all waves' K reads complete first) ---
  __builtin_amdgcn_s_barrier();
#pragma unroll
  for (int m = 0; m < 3; m++)
#pragma unroll
    for (int nf = 0; nf < 12; nf++)
#pragma unroll
      for (int j = 0; j < 4; j++) {
        const int q = wv * 48 + m * 16 + g4 * 4 + j;   // local 0..95
        const int c = nf * 16 + l15;
        Pl[q * 192 + (((c >> 3) ^ (q & 7)) * 8) + (c & 7)] =
            (__bf16)(sacc[m][nf][j] * inv[m][j]);
      }
  asm volatile("s_waitcnt lgkmcnt(0)" ::: "memory");
  __builtin_amdgcn_sched_barrier(0);
  __builtin_amdgcn_s_barrier();   // P complete before cross-wave PV reads

  // --- O = P V (wave-local P rows) ---
  f32x4 oacc[3][8];
#pragma unroll
  for (int m = 0; m < 3; m++)
#pragma unroll
    for (int nf = 0; nf < 8; nf++) oacc[m][nf] = (f32x4)(0.f);
#pragma unroll
  for (int ks = 0; ks < 6; ks++) {
    bf16x8 pf[3];
#pragma unroll
    for (int m = 0; m < 3; m++) {
      const int q = wv * 48 + m * 16 + l15;            // local
      const int sl = (ks * 4 + g4) ^ (q & 7);
      pf[m] = *(const bf16x8*)&Pl[q * 192 + sl * 8];
    }
#pragma unroll
    for (int nf = 0; nf < 8; nf++) {
      const int d = nf * 16 + l15;
      const int sl = ((ks & 1) * 4 + g4) ^ (d & 7);
      const bf16x8 vf = *(const bf16x8*)&Vl[(ks >> 1) * 8192 + d * 64 + sl * 8];
#pragma unroll
      for (int m = 0; m < 3; m++)
        oacc[m][nf] = __builtin_amdgcn_mfma_f32_16x16x32_bf16(pf[m], vf,
                                                              oacc[m][nf], 0, 0, 0);
    }
  }

  // --- write O into packed ob layout ---
  const int b = bh >> 3, hh = bh & 7;
#pragma unroll
  for (int m = 0; m < 3; m++)
#pragma unroll
    for (int nf = 0; nf < 8; nf++) {
      const int d = nf * 16 + l15;
#pragma unroll
      for (int j = 0; j < 4; j++) {
        const int tq = q0 + wv * 48 + m * 16 + g4 * 4 + j;
        ob[((size_t)(b * T + tq)) * D + hh * HD + d] = (__bf16)oacc[m][nf][j];
      }
    }
}

// ---------------------------------------------------------------------------
// Decoder GEMM: logits[MD,V] = zb[MD,D] * DecT[V,D]^T + db.
// 256x256x64 tile, 512 thr / 8 waves (2Mx4N), 128KB dynamic LDS, 2-buffer
// counted-vmcnt(8), 2 MFMA sub-phases per K-tile; XCD-chunked M-fastest
// swizzle; 4-pass LDS-staged f32 epilogue (full 128B lines).
// ---------------------------------------------------------------------------
static constexpr int DEC_NT = (V + 255) / 256;        // 392
static constexpr int DEC_NWG = 8 * DEC_NT;            // 3136 (div by 8)

__global__ __launch_bounds__(512, 2) void k_dec(const __bf16* __restrict__ A,
                                                const __bf16* __restrict__ Bt,
                                                const float* __restrict__ bias,
                                                float* __restrict__ C) {
  extern __shared__ char smem[];
  __bf16* lds = (__bf16*)smem;         // 65536 bf16 = 128 KB
  float* cbuf = (float*)smem;          // epilogue alias: 64 x 256 f32 (64 KB)

  const int bid = blockIdx.x;
  const int swz = (bid & 7) * DEC_NT + (bid >> 3);
  const int tm = (swz & 7) * 256, tn = (swz >> 3) * 256;
  const int tid = threadIdx.x;
  const int lane = tid & 63, wv = tid >> 6;
  const int wm = wv >> 2, wn = wv & 3;         // 2x4 wave grid, 128x64 each
  const int g4 = lane >> 4, l15 = lane & 15;

  f32x4 acc[8][4];
#pragma unroll
  for (int m = 0; m < 8; m++)
#pragma unroll
    for (int n = 0; n < 4; n++) acc[m][n] = (f32x4)(0.f);

  // staging: round i: local row = (tid>>3)+i*64, phys 16B-slot = tid&7,
  // logical k-slot = (tid&7)^(row&7) -> pre-swizzled global k offset.
  const int srow = tid >> 3;                          // 0..63
  const int lcol = (((tid & 7) ^ (srow & 7)) * 8);    // bf16 elems
  int arows[4], brows[4];
#pragma unroll
  for (int i = 0; i < 4; i++) {
    arows[i] = tm + i * 64 + srow;                    // M=2048, in range
    int br = tn + i * 64 + srow; if (br > V - 1) br = V - 1;
    brows[i] = br;
  }

  auto stage = [&](int buf, int kk) {
    __bf16* Abuf = lds + buf * 32768;
    __bf16* Bbuf = lds + 16384 + buf * 32768;
#pragma unroll
    for (int i = 0; i < 4; i++)
      gload16(A + (size_t)arows[i] * D + kk + lcol, Abuf + i * 4096 + (size_t)tid * 8);
#pragma unroll
    for (int i = 0; i < 4; i++)
      gload16(Bt + (size_t)brows[i] * D + kk + lcol, Bbuf + i * 4096 + (size_t)tid * 8);
  };

  // compute one K-tile (64 wide): 2 sub-phases (ks=0,1), 32 MFMA each.
  auto compute = [&](int cur) {
    const __bf16* Abuf = lds + cur * 32768;
    const __bf16* Bbuf = lds + 16384 + cur * 32768;
    bf16x8 af[8], bfv[4];
    // --- ks = 0 ---
#pragma unroll
    for (int m = 0; m < 8; m++) {
      const int row = wm * 128 + m * 16 + l15;
      af[m] = *(const bf16x8*)&Abuf[row * 64 + (g4 ^ (row & 7)) * 8];
    }
#pragma unroll
    for (int n = 0; n < 4; n++) {
      const int row = wn * 64 + n * 16 + l15;
      bfv[n] = *(const bf16x8*)&Bbuf[row * 64 + (g4 ^ (row & 7)) * 8];
    }
    asm volatile("s_waitcnt lgkmcnt(0)" ::: "memory");
    __builtin_amdgcn_sched_barrier(0);
#pragma unroll
    for (int m = 0; m < 8; m++)
#pragma unroll
      for (int n = 0; n < 4; n++)
        acc[m][n] = __builtin_amdgcn_mfma_f32_16x16x32_bf16(af[m], bfv[n],
                                                            acc[m][n], 0, 0, 0);
    // --- ks = 1 ---
#pragma unroll
    for (int m = 0; m < 8; m++) {
      const int row = wm * 128 + m * 16 + l15;
      af[m] = *(const bf16x8*)&Abuf[row * 64 + ((4 + g4) ^ (row & 7)) * 8];
    }
#pragma unroll
    for (int n = 0; n < 4; n++) {
      const int row = wn * 64 + n * 16 + l15;
      bfv[n] = *(const bf16x8*)&Bbuf[row * 64 + ((4 + g4) ^ (row & 7)) * 8];
    }
    asm volatile("s_waitcnt lgkmcnt(0)" ::: "memory");
    __builtin_amdgcn_sched_barrier(0);
    __builtin_amdgcn_s_barrier();   // all waves done reading buf[cur]
#pragma unroll
    for (int m = 0; m < 8; m++)
#pragma unroll
      for (int n = 0; n < 4; n++)
        acc[m][n] = __builtin_amdgcn_mfma_f32_16x16x32_bf16(af[m], bfv[n],
                                                            acc[m][n], 0, 0, 0);
  };

  const int NT = D / 64;           // 16 K-tiles
  stage(0, 0);
  for (int it = 0; it < NT - 1; ++it) {
    const int cur = it & 1;
    stage(cur ^ 1, (it + 1) << 6);                    // 8 loads in flight
    asm volatile("s_waitcnt vmcnt(8)" ::: "memory");  // tile-cur loads landed
    __builtin_amdgcn_s_barrier();
    compute(cur);
  }
  asm volatile("s_waitcnt vmcnt(0)" ::: "memory");
  __builtin_amdgcn_s_barrier();
  compute((NT - 1) & 1);
  __syncthreads();   // all waves past compute barrier; cbuf aliasing safe

  // --- LDS-staged epilogue: 4 passes of 64 rows x 256 cols, full-line stores
  const bool full = (tn + 256 <= V);
  for (int pass = 0; pass < 4; ++pass) {
    if (pass) __syncthreads();           // prior pass reads done
    if (wm == (pass >> 1)) {
      const int mfb = (pass & 1) * 4;
#pragma unroll
      for (int n = 0; n < 4; n++) {
        const int col = wn * 64 + n * 16 + l15;
        const float bsv = (tn + col < V) ? bias[tn + col] : 0.f;
#pragma unroll
        for (int m2 = 0; m2 < 4; m2++) {
#pragma unroll
          for (int j = 0; j < 4; j++) {
            const int row = m2 * 16 + g4 * 4 + j;           // 0..63 in pass
            const int phys = (col >> 2) ^ (row & 7);        // 16B-slot swz
            cbuf[row * 256 + phys * 4 + (col & 3)] = acc[mfb + m2][n][j] + bsv;
          }
        }
      }
    }
    __syncthreads();
    const int rbase = tm + pass * 64;
    if (full) {
      const int row = tid >> 3, c8 = tid & 7;               // 64 rows x 8 lanes
#pragma unroll
      for (int i = 0; i < 8; ++i) {
        const int ps = (c8 ^ (row & 7)) + i * 8;            // phys slot
        const f32x4 v = *(const f32x4*)&cbuf[row * 256 + ps * 4];
        *(f32x4*)&C[(size_t)(rbase + row) * V + tn + (c8 + i * 8) * 4] = v;
      }
    } else {
      for (int idx = tid; idx < 64 * 256; idx += 512) {
        const int row = idx >> 8, col = idx & 255;
        if (tn + col < V)
          C[(size_t)(rbase + row) * V + tn + col] =
              cbuf[row * 256 + (((col >> 2) ^ (row & 7)) << 2) + (col & 3)];
      }
    }
  }
}

// ---------------------------------------------------------------------------
// transpose-cast: in f32 (R,C) -> out bf16 (C,R); vectorized bf16x4 stores.
// ---------------------------------------------------------------------------
__global__ __launch_bounds__(256) void k_transpose(const float* __restrict__ in,
                                                   __bf16* __restrict__ out,
                                                   int R, int C) {
  __shared__ __bf16 tile[32][33];
  const int c0 = blockIdx.x * 32, r0 = blockIdx.y * 32;
  const int tx = threadIdx.x & 31, ty = threadIdx.x >> 5;  // 32x8
#pragma unroll
  for (int i = 0; i < 32; i += 8) {
    const int r = r0 + ty + i, c = c0 + tx;
    tile[ty + i][tx] = (r < R && c < C) ? (__bf16)in[(size_t)r * C + c] : (__bf16)0.f;
  }
  __syncthreads();
  const int oc = threadIdx.x >> 3, rch = (threadIdx.x & 7) * 4;
  const int occ = c0 + oc, orr = r0 + rch;
  if (occ < C && orr + 3 < R) {
    bf16x4 v;
#pragma unroll
    for (int j = 0; j < 4; j++) v[j] = tile[rch + j][oc];
    *(bf16x4*)(out + (size_t)occ * R + orr) = v;
  }
}

// batched (1024,1024) transpose-cast: z selects {wq,wk,wv,wo}; first three
// go to WqkvT slabs, wo to WoT.
__global__ __launch_bounds__(256) void k_transpose4(const float* __restrict__ s0,
                                                    const float* __restrict__ s1,
                                                    const float* __restrict__ s2,
                                                    const float* __restrict__ s3,
                                                    __bf16* __restrict__ dqkv,
                                                    __bf16* __restrict__ dwo) {
  __shared__ __bf16 tile[32][33];
  const int zz = blockIdx.z;
  const float* in = (zz == 0) ? s0 : (zz == 1) ? s1 : (zz == 2) ? s2 : s3;
  __bf16* out = (zz == 3) ? dwo : dqkv + (size_t)zz * D * D;
  const int c0 = blockIdx.x * 32, r0 = blockIdx.y * 32;
  const int tx = threadIdx.x & 31, ty = threadIdx.x >> 5;  // 32x8
#pragma unroll
  for (int i = 0; i < 32; i += 8)
    tile[ty + i][tx] = (__bf16)in[(size_t)(r0 + ty + i) * D + c0 + tx];
  __syncthreads();
  const int oc = threadIdx.x >> 3, rch = (threadIdx.x & 7) * 4;
  bf16x4 v;
#pragma unroll
  for (int j = 0; j < 4; j++) v[j] = tile[rch + j][oc];
  *(bf16x4*)(out + (size_t)(c0 + oc) * D + r0 + rch) = v;
}

__global__ __launch_bounds__(256) void k_concat_bias(const float* bq,
                                                     const float* bk,
                                                     const float* bv,
                                                     float* out) {
  const int i = blockIdx.x * 256 + threadIdx.x;
  if (i < D) { out[i] = bq[i]; out[D + i] = bk[i]; out[2 * D + i] = bv[i]; }
}

__global__ __launch_bounds__(256) void k_rope_table(float* __restrict__ ct,
                                                    float* __restrict__ st) {
  const int i = blockIdx.x * 256 + threadIdx.x;
  if (i < T * 64) {
    const int t = i >> 6, j = i & 63;
    const float inv = expf(-((float)(2 * j) * (1.f / 128.f)) * 9.210340371976184f);
    const float ang = (float)t * inv;
    ct[i] = cosf(ang);
    st[i] = sinf(ang);
  }
}

__global__ __launch_bounds__(256) void k_build_z(const int* __restrict__ tokens,
                                                 const float* __restrict__ embed,
                                                 const float* __restrict__ scratch,
                                                 float* __restrict__ z) {
  const int row = blockIdx.x;  // b*T + t
  const int b = row / T, t = row % T;
  const float* src = (t < S) ? embed + (size_t)tokens[b * S + t] * D
                             : scratch + (size_t)(t - S) * D;
  ((float4*)(z + (size_t)row * D))[threadIdx.x] =
      ((const float4*)src)[threadIdx.x];
}

// z (+= te), h = LN(z)*s + b  (bf16 out)
template <bool ADDT>
__global__ __launch_bounds__(256) void k_ln(float* __restrict__ z,
                                            const float* __restrict__ te,
                                            const float* __restrict__ gs,
                                            const float* __restrict__ gb,
                                            __bf16* __restrict__ h) {
  const int row = blockIdx.x, tid = threadIdx.x;
  float* zp = z + (size_t)row * D;
  float4 x = ((float4*)zp)[tid];
  if (ADDT) {
    const float4 t4 = ((const float4*)te)[tid];
    x.x += t4.x; x.y += t4.y; x.z += t4.z; x.w += t4.w;
    ((float4*)zp)[tid] = x;
  }
  float s = x.x + x.y + x.z + x.w;
  float s2 = x.x * x.x + x.y * x.y + x.z * x.z + x.w * x.w;
#pragma unroll
  for (int o = 32; o; o >>= 1) { s += __shfl_xor(s, o); s2 += __shfl_xor(s2, o); }
  __shared__ float rs[4], rq[4];
  const int wv = tid >> 6, ln = tid & 63;
  if (!ln) { rs[wv] = s; rq[wv] = s2; }
  __syncthreads();
  s = rs[0] + rs[1] + rs[2] + rs[3];
  s2 = rq[0] + rq[1] + rq[2] + rq[3];
  const float mu = s * (1.f / D);
  const float var = s2 * (1.f / D) - mu * mu;
  const float rinv = 1.0f / sqrtf(var + 1e-6f);
  const int c = tid * 4;
  const float4 g4 = ((const float4*)gs)[tid];
  const float4 b4 = ((const float4*)gb)[tid];
  bf16x4 o4;
  o4[0] = (__bf16)((x.x - mu) * rinv * g4.x + b4.x);
  o4[1] = (__bf16)((x.y - mu) * rinv * g4.y + b4.y);
  o4[2] = (__bf16)((x.z - mu) * rinv * g4.z + b4.z);
  o4[3] = (__bf16)((x.w - mu) * rinv * g4.w + b4.w);
  *(bf16x4*)(h + (size_t)row * D + c) = o4;
}

__global__ __launch_bounds__(256) void k_halt(const float* __restrict__ z,
                                              const float* __restrict__ hw,
                                              const float* __restrict__ hb,
                                              float* __restrict__ out) {
  const int b = blockIdx.x, tid = threadIdx.x;
  const float4 w4 = ((const float4*)hw)[tid];
  float acc = 0.f;
  for (int j = 0; j < SCR; j++) {
    const float4 x = ((const float4*)(z + ((size_t)(b * T + S + j)) * D))[tid];
    acc += x.x * w4.x + x.y * w4.y + x.z * w4.z + x.w * w4.w;
  }
#pragma unroll
  for (int o = 32; o; o >>= 1) acc += __shfl_xor(acc, o);
  __shared__ float rs[4];
  const int wv = tid >> 6, ln = tid & 63;
  if (!ln) rs[wv] = acc;
  __syncthreads();
  if (tid == 0) {
    const float tot = rs[0] + rs[1] + rs[2] + rs[3];
    out[b] = 1.f / (1.f + expf(-(tot * (1.f / SCR) + hb[0])));
  }
}

// compact cast: zb[b*S+s] = bf16(z[b*T+s]), only token rows
__global__ __launch_bounds__(256) void k_cast(const float* __restrict__ z,
                                              __bf16* __restrict__ zb) {
  const int row = blockIdx.x;            // b*S + s
  const int b = row >> 7, s = row & 127; // S = 128
  const float4 x = ((const float4*)(z + ((size_t)(b * T + s)) * D))[threadIdx.x];
  bf16x4 o;
  o[0] = (__bf16)x.x; o[1] = (__bf16)x.y; o[2] = (__bf16)x.z; o[3] = (__bf16)x.w;
  *(bf16x4*)(zb + (size_t)row * D + threadIdx.x * 4) = o;
}

// ---------------------------------------------------------------------------
extern "C" void kernel_launch(void* const* d_in, const int* in_sizes, int n_in,
                              void* d_out, int out_size, void* d_ws,
                              size_t ws_size, hipStream_t stream) {
  const int* tokens = (const int*)d_in[0];
  const float* embed = (const float*)d_in[1];
  const float* time_embed = (const float*)d_in[2];
  const float* scratch = (const float*)d_in[3];
  const float* wq = (const float*)d_in[4];  const float* bq = (const float*)d_in[5];
  const float* wk = (const float*)d_in[6];  const float* bk = (const float*)d_in[7];
  const float* wvv = (const float*)d_in[8]; const float* bv = (const float*)d_in[9];
  const float* wo = (const float*)d_in[10]; const float* bo = (const float*)d_in[11];
  const float* ln1s = (const float*)d_in[12]; const float* ln1b = (const float*)d_in[13];
  const float* ln2s = (const float*)d_in[14]; const float* ln2b = (const float*)d_in[15];
  const float* w1 = (const float*)d_in[16]; const float* b1 = (const float*)d_in[17];
  const float* w2 = (const float*)d_in[18]; const float* b2 = (const float*)d_in[19];
  const float* hw = (const float*)d_in[20]; const float* hb = (const float*)d_in[21];
  const float* dw = (const float*)d_in[22]; const float* db = (const float*)d_in[23];

  char* w = (char*)d_ws;
  size_t off = 0;
  auto al = [&](size_t n) { size_t o = off; off += (n + 255) & ~(size_t)255; return o; };
  const size_t oWqkvT = al((size_t)3 * D * D * 2);
  const size_t oWoT   = al((size_t)D * D * 2);
  const size_t oW1T   = al((size_t)DFF * D * 2);
  const size_t oW2T   = al((size_t)D * DFF * 2);
  const size_t oDecT  = al((size_t)V * D * 2);
  const size_t oBqkv  = al((size_t)3 * D * 4);
  const size_t oCt    = al((size_t)T * 64 * 4);
  const size_t oSt    = al((size_t)T * 64 * 4);
  const size_t oZ     = al((size_t)ROWS * D * 4);
  const size_t oH     = al((size_t)ROWS * D * 2);   // h; later zb alias
  const size_t oG     = al((size_t)ROWS * DFF * 2); // gelu out (bf16)
  const size_t oOB    = al((size_t)ROWS * D * 2);   // attn out packed (bf16)
  const size_t oQ     = al(QSZ * 2);
  const size_t oK     = al(QSZ * 2);
  const size_t oVT    = al(QSZ * 2);
  (void)ws_size; (void)in_sizes; (void)n_in; (void)out_size;

  __bf16* WqkvT = (__bf16*)(w + oWqkvT);
  __bf16* WoT   = (__bf16*)(w + oWoT);
  __bf16* W1T   = (__bf16*)(w + oW1T);
  __bf16* W2T   = (__bf16*)(w + oW2T);
  __bf16* DecT  = (__bf16*)(w + oDecT);
  float*  bqkv  = (float*)(w + oBqkv);
  float*  ct    = (float*)(w + oCt);
  float*  st    = (float*)(w + oSt);
  float*  z     = (float*)(w + oZ);
  __bf16* h     = (__bf16*)(w + oH);
  __bf16* g     = (__bf16*)(w + oG);
  __bf16* ob    = (__bf16*)(w + oOB);
  __bf16* qb    = (__bf16*)(w + oQ);    // qb|kb|vT contiguous (EPI=5 relies on QSZ offsets)
  __bf16* kb    = (__bf16*)(w + oK);
  __bf16* vT    = (__bf16*)(w + oVT);
  __bf16* zb    = (__bf16*)(w + oH);    // alias (h dead at decode time)

  float* logits = (float*)d_out;
  float* halts  = (float*)d_out + LOGITS;

  // --- weight prep (runs every call; deterministic) ---
  k_transpose4<<<dim3(32, 32, 4), 256, 0, stream>>>(wq, wk, wvv, wo, WqkvT, WoT);
  k_transpose<<<dim3(128, 32), 256, 0, stream>>>(w1, W1T, D, DFF);
  k_transpose<<<dim3(32, 128), 256, 0, stream>>>(w2, W2T, DFF, D);
  k_transpose<<<dim3((V + 31) / 32, 32), 256, 0, stream>>>(dw, DecT, D, V);
  k_concat_bias<<<4, 256, 0, stream>>>(bq, bk, bv, bqkv);
  k_rope_table<<<(T * 64 + 255) / 256, 256, 0, stream>>>(ct, st);
  k_build_z<<<ROWS, 256, 0, stream>>>(tokens, embed, scratch, z);

  for (int step = 0; step < NSTEP; step++) {
    k_ln<true><<<ROWS, 256, 0, stream>>>(z, time_embed + (size_t)step * D, ln1s, ln1b, h);
    // QKV (3072,1024)x(1024,3072) + rope fused -> qb/kb/vT directly
    k_gemm<5><<<dim3(24, 24, 1), 256, 65536, stream>>>(h, 0, D, ROWS, WqkvT, 0, D,
                                                       3 * D, D, bqkv, qb, 0, 0, ct, st);
    // fused attention: 2 blocks per (b,h), scores + softmax + PV -> ob
    k_attn<<<BB * H * 2, 128, 98304, stream>>>(qb, kb, vT, ob);
    // WO + residual into z
    k_gemm<1><<<dim3(8, 24, 1), 256, 65536, stream>>>(ob, 0, D, ROWS, WoT, 0, D, D,
                                                      D, bo, z, 0, D, nullptr, nullptr);
    k_ln<false><<<ROWS, 256, 0, stream>>>(z, nullptr, ln2s, ln2b, h);
    // MLP1 + gelu -> bf16
    k_gemm<2><<<dim3(32, 24, 1), 256, 65536, stream>>>(h, 0, D, ROWS, W1T, 0, D,
                                                       DFF, D, b1, g, 0, DFF, nullptr, nullptr);
    // MLP2 + residual into z: split-K=4 (chunks of 1024), atomicAdd epilogue
    k_gemm<4><<<dim3(8, 24, 4), 256, 65536, stream>>>(g, 0, DFF, ROWS, W2T, 0, DFF,
                                                      D, DFF / 4, b2, z, 0, D, nullptr, nullptr);
    k_halt<<<BB, 256, 0, stream>>>(z, hw, hb, halts + step * BB);
  }

  // decoder: one merged (2048,1024) x (1024,100277) GEMM, 256x256x64 tiles
  k_cast<<<MD, 256, 0, stream>>>(z, zb);
  k_dec<<<DEC_NWG, 512, 131072, stream>>>(zb, DecT, db, logits);
}

// Round 18
// 2706.729 us; speedup vs baseline: 1.0612x; 1.0013x over previous
//
#include <hip/hip_runtime.h>
#include <hip/hip_bf16.h>
#include <math.h>

// ---------------------------------------------------------------------------
// UniversalReasoner: 8-step recurrent transformer + vocab decoder, MI355X.
// Round 18: k_dec LDS/MFMA overlap — K-tile split into 4 {reads,MFMA}
// sections with 1-chunk read lookahead, pinned by sched_barrier(0) fences.
// Counted (compiler) lgkmcnt lets section c+1 reads complete under section
// c's MFMAs, de-bursting the lockstep LDS->MFMA alternation (k_dec was
// co-limited: 192 b128 ~2300cyc vs 512 MFMA ~2480cyc per K-tile per CU).
// Release barrier unchanged (full lgkmcnt(0) drain before s_barrier).
// k_gemm / k_attn / everything else identical to R17.
// ---------------------------------------------------------------------------

typedef float  f32x4  __attribute__((ext_vector_type(4)));
typedef __bf16 bf16x8 __attribute__((ext_vector_type(8)));
typedef __bf16 bf16x4 __attribute__((ext_vector_type(4)));

static constexpr int BB   = 16;     // batch
static constexpr int S    = 128;    // sequence tokens
static constexpr int SCR  = 64;     // scratch tokens
static constexpr int T    = 192;    // S + SCR
static constexpr int D    = 1024;
static constexpr int H    = 8;
static constexpr int HD   = 128;
static constexpr int DFF  = 4096;
static constexpr int NSTEP= 8;
static constexpr int V    = 100277;
static constexpr int ROWS = BB * T; // 3072
static constexpr int MD   = BB * S; // 2048 decoder rows
static constexpr long long LOGITS = (long long)BB * S * V; // 205367296
static constexpr size_t QSZ = (size_t)BB * H * T * HD;     // per q/k/v tensor

#define DEV __device__ __forceinline__

DEV void gload16(const __bf16* g, __bf16* l) {
  __builtin_amdgcn_global_load_lds(
      (__attribute__((address_space(1))) void*)(g),
      (__attribute__((address_space(3))) void*)(l), 16, 0, 0);
}

// ---------------------------------------------------------------------------
// Workhorse GEMM (128x128x64):  C[M,N] = A[M,K] * Bt[N,K]^T (+epilogue)
// EPI: 1 = bias + in-place f32 residual add ; 2 = bias + gelu -> bf16 ;
//      4 = split-K: bz = k-chunk, atomicAdd into f32 C, bias only on bz==0 ;
//      5 = QKV+rope: writes q/k bf16 (rope'd) and vT bf16 via kind = tn>>10.
// Requires K % 64 == 0. Launch with 65536 B dynamic LDS.
// ---------------------------------------------------------------------------
template <int EPI>
__global__ __launch_bounds__(256) void k_gemm(
    const __bf16* __restrict__ A, long long sA, int ldA, int M,
    const __bf16* __restrict__ Bt, long long sB, int ldB, int N, int K,
    const float* __restrict__ bias, void* __restrict__ C, long long sC,
    int ldC, const float* __restrict__ rct, const float* __restrict__ rst) {
  extern __shared__ char smem[];
  __bf16* lds = (__bf16*)smem;   // A(buf)=lds+buf*16384; B(buf)=+8192

  const int bz = blockIdx.z;
  const __bf16* Ab;
  const __bf16* Bb;
  if constexpr (EPI == 4) {
    Ab = A + (size_t)bz * K;   // k-chunk offset within row
    Bb = Bt + (size_t)bz * K;
  } else {
    Ab = A + (size_t)bz * sA;
    Bb = Bt + (size_t)bz * sB;
  }
  const int tm = blockIdx.y * 128, tn = blockIdx.x * 128;
  const int tid = threadIdx.x;
  const int lane = tid & 63, wv = tid >> 6;
  const int wr = wv >> 1, wc = wv & 1;  // 2x2 wave grid, 64x64 per wave
  const int g4 = lane >> 4, l15 = lane & 15;

  f32x4 acc[4][4];
#pragma unroll
  for (int m = 0; m < 4; m++)
#pragma unroll
    for (int n = 0; n < 4; n++) acc[m][n] = (f32x4)(0.f);

  // staging: chunk = i*256+tid -> local row = i*32 + (tid>>3), phys slot tid&7
  const int srow = tid >> 3;                          // 0..31
  const int lcol = (((tid & 7) ^ (srow & 7)) * 8);    // pre-swizzled k offset
  int arows[4], brows[4];
#pragma unroll
  for (int i = 0; i < 4; i++) {
    int ar = tm + i * 32 + srow; if (ar > M - 1) ar = M - 1;
    int br = tn + i * 32 + srow; if (br > N - 1) br = N - 1;
    arows[i] = ar; brows[i] = br;
  }

  auto stage = [&](int buf, int kk) {
    __bf16* Abuf = lds + buf * 16384;
    __bf16* Bbuf = lds + 8192 + buf * 16384;
#pragma unroll
    for (int i = 0; i < 4; i++)
      gload16(Ab + (size_t)arows[i] * ldA + kk + lcol, Abuf + i * 2048 + (size_t)tid * 8);
#pragma unroll
    for (int i = 0; i < 4; i++)
      gload16(Bb + (size_t)brows[i] * ldB + kk + lcol, Bbuf + i * 2048 + (size_t)tid * 8);
  };

  // one K-tile (64 wide): 2 sub-phases, 16 MFMA each (32 per wave).
  auto compute = [&](int cur) {
    const __bf16* Abuf = lds + cur * 16384;
    const __bf16* Bbuf = lds + 8192 + cur * 16384;
    bf16x8 af[4], bfv[4];
    // --- ks = 0 ---
#pragma unroll
    for (int m = 0; m < 4; m++) {
      const int row = wr * 64 + m * 16 + l15;
      af[m] = *(const bf16x8*)&Abuf[row * 64 + (g4 ^ (row & 7)) * 8];
    }
#pragma unroll
    for (int n = 0; n < 4; n++) {
      const int row = wc * 64 + n * 16 + l15;
      bfv[n] = *(const bf16x8*)&Bbuf[row * 64 + (g4 ^ (row & 7)) * 8];
    }
    asm volatile("s_waitcnt lgkmcnt(0)" ::: "memory");
    __builtin_amdgcn_sched_barrier(0);
#pragma unroll
    for (int m = 0; m < 4; m++)
#pragma unroll
      for (int n = 0; n < 4; n++)
        acc[m][n] = __builtin_amdgcn_mfma_f32_16x16x32_bf16(af[m], bfv[n],
                                                            acc[m][n], 0, 0, 0);
    // --- ks = 1 ---
#pragma unroll
    for (int m = 0; m < 4; m++) {
      const int row = wr * 64 + m * 16 + l15;
      af[m] = *(const bf16x8*)&Abuf[row * 64 + ((4 + g4) ^ (row & 7)) * 8];
    }
#pragma unroll
    for (int n = 0; n < 4; n++) {
      const int row = wc * 64 + n * 16 + l15;
      bfv[n] = *(const bf16x8*)&Bbuf[row * 64 + ((4 + g4) ^ (row & 7)) * 8];
    }
    asm volatile("s_waitcnt lgkmcnt(0)" ::: "memory");
    __builtin_amdgcn_sched_barrier(0);
    __builtin_amdgcn_s_barrier();   // all waves done reading buf[cur]
#pragma unroll
    for (int m = 0; m < 4; m++)
#pragma unroll
      for (int n = 0; n < 4; n++)
        acc[m][n] = __builtin_amdgcn_mfma_f32_16x16x32_bf16(af[m], bfv[n],
                                                            acc[m][n], 0, 0, 0);
  };

  const int NT = K >> 6;           // K-tiles of 64 (K % 64 == 0)
  stage(0, 0);
  for (int it = 0; it < NT - 1; ++it) {
    const int cur = it & 1;
    stage(cur ^ 1, (it + 1) << 6);                    // 8 loads in flight
    asm volatile("s_waitcnt vmcnt(8)" ::: "memory");  // tile-cur loads landed
    __builtin_amdgcn_s_barrier();
    compute(cur);
  }
  asm volatile("s_waitcnt vmcnt(0)" ::: "memory");
  __builtin_amdgcn_s_barrier();
  compute((NT - 1) & 1);

  // epilogue: C/D layout col=lane&15, row=(lane>>4)*4+reg
  const int r0 = tm + wr * 64, c0 = tn + wc * 64;
  if constexpr (EPI == 5) {
    const int kind = tn >> 10;  // 0=q, 1=k, 2=v
#pragma unroll
    for (int n = 0; n < 4; n++) {
      const int c = c0 + n * 16 + (lane & 15);
      const int hh = (c & 1023) >> 7, d = c & 127, jp = d >> 1;
      const float bsv = bias[c];
#pragma unroll
      for (int m = 0; m < 4; m++) {
        const int rb = r0 + m * 16 + ((lane >> 4) << 2);
#pragma unroll
        for (int j = 0; j < 4; j++) {
          const int r = rb + j;
          const float x = acc[m][n][j] + bsv;
          const float xo = __shfl_xor(x, 1);   // pair value (col ^ 1)
          const int b = r / T, t = r % T;
          if (kind == 2) {
            ((__bf16*)C)[2 * QSZ + ((size_t)((b * H + hh) * HD + d)) * T + t] =
                (__bf16)x;
          } else {
            const float cs = rct[t * 64 + jp], sn = rst[t * 64 + jp];
            const float o = (c & 1) ? (x * cs + xo * sn) : (x * cs - xo * sn);
            ((__bf16*)C)[(size_t)kind * QSZ +
                         ((size_t)((b * H + hh) * T + t)) * HD + d] = (__bf16)o;
          }
        }
      }
    }
    return;
  }
#pragma unroll
  for (int n = 0; n < 4; n++) {
    const int c = c0 + n * 16 + (lane & 15);
    if (c >= N) continue;
    const float bsv = (bias && (EPI != 4 || bz == 0)) ? bias[c] : 0.f;
#pragma unroll
    for (int m = 0; m < 4; m++) {
      const int rb = r0 + m * 16 + ((lane >> 4) << 2);
#pragma unroll
      for (int j = 0; j < 4; j++) {
        const int r = rb + j;
        if (r >= M) continue;
        float x = acc[m][n][j] + bsv;
        if constexpr (EPI == 4) {
          atomicAdd((float*)C + (size_t)r * ldC + c, x);
        } else {
          const size_t idx = (size_t)bz * sC + (size_t)r * ldC + c;
          if constexpr (EPI == 2) {
            const float u = x;
            const float gl =
                0.5f * u * (1.f + tanhf(0.7978845608f * (u + 0.044715f * u * u * u)));
            ((__bf16*)C)[idx] = (__bf16)gl;
          } else {
            ((float*)C)[idx] += x;
          }
        }
      }
    }
  }
}

// ---------------------------------------------------------------------------
// Fused attention: 2 blocks per (b,h) (Q-halves), 128 thr / 2 waves x 48 rows.
// LDS: K [192][128] swz (48KB, overlaid by P [96][192] after barrier);
//      V^T 3 x [128][64] swz at +49152. dyn 98304 B.
// ---------------------------------------------------------------------------
__global__ __launch_bounds__(128) void k_attn(const __bf16* __restrict__ qb,
                                              const __bf16* __restrict__ kb,
                                              const __bf16* __restrict__ vT,
                                              __bf16* __restrict__ ob) {
  extern __shared__ char smem[];
  __bf16* Kl = (__bf16*)smem;             // [192][128]
  __bf16* Pl = (__bf16*)smem;             // [96][192] (after barrier)
  __bf16* Vl = (__bf16*)(smem + 49152);   // 3 x [128][64]
  const int bid = blockIdx.x;
  const int bh = bid >> 1, q0 = (bid & 1) * 96;   // Q-half base (96 % 8 == 0)
  const int tid = threadIdx.x, lane = tid & 63, wv = tid >> 6;  // wv in {0,1}
  const int g4 = lane >> 4, l15 = lane & 15;
  const size_t hoff = (size_t)bh * T * HD;
  const size_t voff = (size_t)bh * HD * T;

  // --- hoist Q fragments (regs) ---
  bf16x8 qf[3][4];
#pragma unroll
  for (int m = 0; m < 3; m++)
#pragma unroll
    for (int ks = 0; ks < 4; ks++) {
      const int tq = q0 + wv * 48 + m * 16 + l15;
      qf[m][ks] = *(const bf16x8*)(qb + hoff + (size_t)tq * HD + ks * 32 + g4 * 8);
    }

  // --- stage K: 48 chunks (24/wave) of 4 rows x 16 slots(16B), swz source ---
#pragma unroll
  for (int ci = 0; ci < 24; ci++) {
    const int ch = wv * 24 + ci;
    const int grow = ch * 4 + g4;
    const int sl = l15 ^ (grow & 7);
    gload16(kb + hoff + (size_t)grow * HD + sl * 8, Kl + ch * 512);
  }
  // --- stage V^T: 3 subtiles x 16 chunks (24/wave) of 8 rows x 8 slots ---
#pragma unroll
  for (int ci = 0; ci < 24; ci++) {
    const int ch = wv * 24 + ci;
    const int c = ch >> 4, ch2 = ch & 15;
    const int d = ch2 * 8 + (lane >> 3);
    const int sl = (lane & 7) ^ (d & 7);
    gload16(vT + voff + (size_t)d * T + c * 64 + sl * 8,
            Vl + c * 8192 + ch2 * 512);
  }
  asm volatile("s_waitcnt vmcnt(0)" ::: "memory");
  __builtin_amdgcn_s_barrier();

  // --- S = Q K^T ---
  f32x4 sacc[3][12];
#pragma unroll
  for (int m = 0; m < 3; m++)
#pragma unroll
    for (int nf = 0; nf < 12; nf++) sacc[m][nf] = (f32x4)(0.f);
#pragma unroll
  for (int ks = 0; ks < 4; ks++)
#pragma unroll
    for (int nf = 0; nf < 12; nf++) {
      const int row = nf * 16 + l15;
      const int sl = (ks * 4 + g4) ^ (row & 7);
      const bf16x8 kf = *(const bf16x8*)&Kl[row * 128 + sl * 8];
#pragma unroll
      for (int m = 0; m < 3; m++)
        sacc[m][nf] = __builtin_amdgcn_mfma_f32_16x16x32_bf16(qf[m][ks], kf,
                                                              sacc[m][nf], 0, 0, 0);
    }

  // --- softmax (scale, causal mask, in-reg row reduce) ---
  const float scale = 0.08838834764831845f;
  float inv[3][4];
#pragma unroll
  for (int m = 0; m < 3; m++)
#pragma unroll
    for (int j = 0; j < 4; j++) {
      const int tq = q0 + wv * 48 + m * 16 + g4 * 4 + j;
#pragma unroll
      for (int nf = 0; nf < 12; nf++) {
        const int c = nf * 16 + l15;
        float v = sacc[m][nf][j] * scale;
        if (tq < S && c > tq) v = -1e30f;
        sacc[m][nf][j] = v;
      }
      float mm = -1e30f;
#pragma unroll
      for (int nf = 0; nf < 12; nf++) mm = fmaxf(mm, sacc[m][nf][j]);
#pragma unroll
      for (int o = 1; o < 16; o <<= 1) mm = fmaxf(mm, __shfl_xor(mm, o));
      float sum = 0.f;
#pragma unroll
      for (int nf = 0; nf < 12; nf++) {
        const float e = __expf(sacc[m][nf][j] - mm);
        sacc[m][nf][j] = e;
        sum += e;
      }
#pragma unroll
      for (int o = 1; o < 16; o <<= 1) sum += __shfl_xor(sum, o);
      inv[m][j] = 1.f / sum;
    }

  // --- P to LDS (overlays K; all waves' K reads complete first) ---
  __builtin_amdgcn_s_barrier();
#pragma unroll
  for (int m = 0; m < 3; m++)
#pragma unroll
    for (int nf = 0; nf < 12; nf++)
#pragma unroll
      for (int j = 0; j < 4; j++) {
        const int q = wv * 48 + m * 16 + g4 * 4 + j;   // local 0..95
        const int c = nf * 16 + l15;
        Pl[q * 192 + (((c >> 3) ^ (q & 7)) * 8) + (c & 7)] =
            (__bf16)(sacc[m][nf][j] * inv[m][j]);
      }
  asm volatile("s_waitcnt lgkmcnt(0)" ::: "memory");
  __builtin_amdgcn_sched_barrier(0);
  __builtin_amdgcn_s_barrier();   // P complete before cross-wave PV reads

  // --- O = P V (wave-local P rows) ---
  f32x4 oacc[3][8];
#pragma unroll
  for (int m = 0; m < 3; m++)
#pragma unroll
    for (int nf = 0; nf < 8; nf++) oacc[m][nf] = (f32x4)(0.f);
#pragma unroll
  for (int ks = 0; ks < 6; ks++) {
    bf16x8 pf[3];
#pragma unroll
    for (int m = 0; m < 3; m++) {
      const int q = wv * 48 + m * 16 + l15;            // local
      const int sl = (ks * 4 + g4) ^ (q & 7);
      pf[m] = *(const bf16x8*)&Pl[q * 192 + sl * 8];
    }
#pragma unroll
    for (int nf = 0; nf < 8; nf++) {
      const int d = nf * 16 + l15;
      const int sl = ((ks & 1) * 4 + g4) ^ (d & 7);
      const bf16x8 vf = *(const bf16x8*)&Vl[(ks >> 1) * 8192 + d * 64 + sl * 8];
#pragma unroll
      for (int m = 0; m < 3; m++)
        oacc[m][nf] = __builtin_amdgcn_mfma_f32_16x16x32_bf16(pf[m], vf,
                                                              oacc[m][nf], 0, 0, 0);
    }
  }

  // --- write O into packed ob layout ---
  const int b = bh >> 3, hh = bh & 7;
#pragma unroll
  for (int m = 0; m < 3; m++)
#pragma unroll
    for (int nf = 0; nf < 8; nf++) {
      const int d = nf * 16 + l15;
#pragma unroll
      for (int j = 0; j < 4; j++) {
        const int tq = q0 + wv * 48 + m * 16 + g4 * 4 + j;
        ob[((size_t)(b * T + tq)) * D + hh * HD + d] = (__bf16)oacc[m][nf][j];
      }
    }
}

// ---------------------------------------------------------------------------
// Decoder GEMM: logits[MD,V] = zb[MD,D] * DecT[V,D]^T + db.
// 256x256x64 tile, 512 thr / 8 waves (2Mx4N), 128KB dynamic LDS, 2-buffer
// counted-vmcnt(8); K-tile split into 4 {reads,MFMA} sections with 1-chunk
// lookahead (counted lgkmcnt overlap); XCD-chunked M-fastest swizzle;
// 4-pass LDS-staged f32 epilogue (full 128B lines).
// ---------------------------------------------------------------------------
static constexpr int DEC_NT = (V + 255) / 256;        // 392
static constexpr int DEC_NWG = 8 * DEC_NT;            // 3136 (div by 8)

__global__ __launch_bounds__(512, 2) void k_dec(const __bf16* __restrict__ A,
                                                const __bf16* __restrict__ Bt,
                                                const float* __restrict__ bias,
                                                float* __restrict__ C) {
  extern __shared__ char smem[];
  __bf16* lds = (__bf16*)smem;         // 65536 bf16 = 128 KB
  float* cbuf = (float*)smem;          // epilogue alias: 64 x 256 f32 (64 KB)

  const int bid = blockIdx.x;
  const int swz = (bid & 7) * DEC_NT + (bid >> 3);
  const int tm = (swz & 7) * 256, tn = (swz >> 3) * 256;
  const int tid = threadIdx.x;
  const int lane = tid & 63, wv = tid >> 6;
  const int wm = wv >> 2, wn = wv & 3;         // 2x4 wave grid, 128x64 each
  const int g4 = lane >> 4, l15 = lane & 15;

  f32x4 acc[8][4];
#pragma unroll
  for (int m = 0; m < 8; m++)
#pragma unroll
    for (int n = 0; n < 4; n++) acc[m][n] = (f32x4)(0.f);

  // staging: round i: local row = (tid>>3)+i*64, phys 16B-slot = tid&7,
  // logical k-slot = (tid&7)^(row&7) -> pre-swizzled global k offset.
  const int srow = tid >> 3;                          // 0..63
  const int lcol = (((tid & 7) ^ (srow & 7)) * 8);    // bf16 elems
  int arows[4], brows[4];
#pragma unroll
  for (int i = 0; i < 4; i++) {
    arows[i] = tm + i * 64 + srow;                    // M=2048, in range
    int br = tn + i * 64 + srow; if (br > V - 1) br = V - 1;
    brows[i] = br;
  }

  auto stage = [&](int buf, int kk) {
    __bf16* Abuf = lds + buf * 32768;
    __bf16* Bbuf = lds + 16384 + buf * 32768;
#pragma unroll
    for (int i = 0; i < 4; i++)
      gload16(A + (size_t)arows[i] * D + kk + lcol, Abuf + i * 4096 + (size_t)tid * 8);
#pragma unroll
    for (int i = 0; i < 4; i++)
      gload16(Bt + (size_t)brows[i] * D + kk + lcol, Bbuf + i * 4096 + (size_t)tid * 8);
  };

  // one K-tile (64): 4 sections of 16 MFMA; reads pipelined 1 section ahead.
  // Sections: (ks0,h0) (ks0,h1) (ks1,h0) (ks1,h1); h = m-half (rows 4h..4h+3).
  auto compute = [&](int cur) {
    const __bf16* Abuf = lds + cur * 32768;
    const __bf16* Bbuf = lds + 16384 + cur * 32768;
    bf16x8 a0[4], a1[4], a2[4], a3[4], b0[4], b1[4];
    // R0: A m=0..3 ks0 + B ks0
#pragma unroll
    for (int m = 0; m < 4; m++) {
      const int row = wm * 128 + m * 16 + l15;
      a0[m] = *(const bf16x8*)&Abuf[row * 64 + (g4 ^ (row & 7)) * 8];
    }
#pragma unroll
    for (int n = 0; n < 4; n++) {
      const int row = wn * 64 + n * 16 + l15;
      b0[n] = *(const bf16x8*)&Bbuf[row * 64 + (g4 ^ (row & 7)) * 8];
    }
    // R1: A m=4..7 ks0
#pragma unroll
    for (int m = 0; m < 4; m++) {
      const int row = wm * 128 + (m + 4) * 16 + l15;
      a1[m] = *(const bf16x8*)&Abuf[row * 64 + (g4 ^ (row & 7)) * 8];
    }
    __builtin_amdgcn_sched_barrier(0);
    // MFMA (ks0,h0): waits only R0 (counted lgkmcnt); R1 in flight
#pragma unroll
    for (int m = 0; m < 4; m++)
#pragma unroll
      for (int n = 0; n < 4; n++)
        acc[m][n] = __builtin_amdgcn_mfma_f32_16x16x32_bf16(a0[m], b0[n],
                                                            acc[m][n], 0, 0, 0);
    __builtin_amdgcn_sched_barrier(0);
    // R2: A m=0..3 ks1 + B ks1
#pragma unroll
    for (int m = 0; m < 4; m++) {
      const int row = wm * 128 + m * 16 + l15;
      a2[m] = *(const bf16x8*)&Abuf[row * 64 + ((4 + g4) ^ (row & 7)) * 8];
    }
#pragma unroll
    for (int n = 0; n < 4; n++) {
      const int row = wn * 64 + n * 16 + l15;
      b1[n] = *(const bf16x8*)&Bbuf[row * 64 + ((4 + g4) ^ (row & 7)) * 8];
    }
    __builtin_amdgcn_sched_barrier(0);
    // MFMA (ks0,h1): waits R1; R2 in flight
#pragma unroll
    for (int m = 0; m < 4; m++)
#pragma unroll
      for (int n = 0; n < 4; n++)
        acc[4 + m][n] = __builtin_amdgcn_mfma_f32_16x16x32_bf16(a1[m], b0[n],
                                                                acc[4 + m][n], 0, 0, 0);
    __builtin_amdgcn_sched_barrier(0);
    // R3: A m=4..7 ks1
#pragma unroll
    for (int m = 0; m < 4; m++) {
      const int row = wm * 128 + (m + 4) * 16 + l15;
      a3[m] = *(const bf16x8*)&Abuf[row * 64 + ((4 + g4) ^ (row & 7)) * 8];
    }
    asm volatile("s_waitcnt lgkmcnt(0)" ::: "memory");
    __builtin_amdgcn_sched_barrier(0);
    __builtin_amdgcn_s_barrier();   // all reads of buf[cur] complete
    // MFMA (ks1,h0)
#pragma unroll
    for (int m = 0; m < 4; m++)
#pragma unroll
      for (int n = 0; n < 4; n++)
        acc[m][n] = __builtin_amdgcn_mfma_f32_16x16x32_bf16(a2[m], b1[n],
                                                            acc[m][n], 0, 0, 0);
    // MFMA (ks1,h1)
#pragma unroll
    for (int m = 0; m < 4; m++)
#pragma unroll
      for (int n = 0; n < 4; n++)
        acc[4 + m][n] = __builtin_amdgcn_mfma_f32_16x16x32_bf16(a3[m], b1[n],
                                                                acc[4 + m][n], 0, 0, 0);
  };

  const int NT = D / 64;           // 16 K-tiles
  stage(0, 0);
  for (int it = 0; it < NT - 1; ++it) {
    const int cur = it & 1;
    stage(cur ^ 1, (it + 1) << 6);                    // 8 loads in flight
    asm volatile("s_waitcnt vmcnt(8)" ::: "memory");  // tile-cur loads landed
    __builtin_amdgcn_s_barrier();
    compute(cur);
  }
  asm volatile("s_waitcnt vmcnt(0)" ::: "memory");
  __builtin_amdgcn_s_barrier();
  compute((NT - 1) & 1);
  __syncthreads();   // all waves past compute barrier; cbuf aliasing safe

  // --- LDS-staged epilogue: 4 passes of 64 rows x 256 cols, full-line stores
  const bool full = (tn + 256 <= V);
  for (int pass = 0; pass < 4; ++pass) {
    if (pass) __syncthreads();           // prior pass reads done
    if (wm == (pass >> 1)) {
      const int mfb = (pass & 1) * 4;
#pragma unroll
      for (int n = 0; n < 4; n++) {
        const int col = wn * 64 + n * 16 + l15;
        const float bsv = (tn + col < V) ? bias[tn + col] : 0.f;
#pragma unroll
        for (int m2 = 0; m2 < 4; m2++) {
#pragma unroll
          for (int j = 0; j < 4; j++) {
            const int row = m2 * 16 + g4 * 4 + j;           // 0..63 in pass
            const int phys = (col >> 2) ^ (row & 7);        // 16B-slot swz
            cbuf[row * 256 + phys * 4 + (col & 3)] = acc[mfb + m2][n][j] + bsv;
          }
        }
      }
    }
    __syncthreads();
    const int rbase = tm + pass * 64;
    if (full) {
      const int row = tid >> 3, c8 = tid & 7;               // 64 rows x 8 lanes
#pragma unroll
      for (int i = 0; i < 8; ++i) {
        const int ps = (c8 ^ (row & 7)) + i * 8;            // phys slot
        const f32x4 v = *(const f32x4*)&cbuf[row * 256 + ps * 4];
        *(f32x4*)&C[(size_t)(rbase + row) * V + tn + (c8 + i * 8) * 4] = v;
      }
    } else {
      for (int idx = tid; idx < 64 * 256; idx += 512) {
        const int row = idx >> 8, col = idx & 255;
        if (tn + col < V)
          C[(size_t)(rbase + row) * V + tn + col] =
              cbuf[row * 256 + (((col >> 2) ^ (row & 7)) << 2) + (col & 3)];
      }
    }
  }
}

// ---------------------------------------------------------------------------
// transpose-cast: in f32 (R,C) -> out bf16 (C,R); vectorized bf16x4 stores.
// ---------------------------------------------------------------------------
__global__ __launch_bounds__(256) void k_transpose(const float* __restrict__ in,
                                                   __bf16* __restrict__ out,
                                                   int R, int C) {
  __shared__ __bf16 tile[32][33];
  const int c0 = blockIdx.x * 32, r0 = blockIdx.y * 32;
  const int tx = threadIdx.x & 31, ty = threadIdx.x >> 5;  // 32x8
#pragma unroll
  for (int i = 0; i < 32; i += 8) {
    const int r = r0 + ty + i, c = c0 + tx;
    tile[ty + i][tx] = (r < R && c < C) ? (__bf16)in[(size_t)r * C + c] : (__bf16)0.f;
  }
  __syncthreads();
  const int oc = threadIdx.x >> 3, rch = (threadIdx.x & 7) * 4;
  const int occ = c0 + oc, orr = r0 + rch;
  if (occ < C && orr + 3 < R) {
    bf16x4 v;
#pragma unroll
    for (int j = 0; j < 4; j++) v[j] = tile[rch + j][oc];
    *(bf16x4*)(out + (size_t)occ * R + orr) = v;
  }
}

// batched (1024,1024) transpose-cast: z selects {wq,wk,wv,wo}; first three
// go to WqkvT slabs, wo to WoT.
__global__ __launch_bounds__(256) void k_transpose4(const float* __restrict__ s0,
                                                    const float* __restrict__ s1,
                                                    const float* __restrict__ s2,
                                                    const float* __restrict__ s3,
                                                    __bf16* __restrict__ dqkv,
                                                    __bf16* __restrict__ dwo) {
  __shared__ __bf16 tile[32][33];
  const int zz = blockIdx.z;
  const float* in = (zz == 0) ? s0 : (zz == 1) ? s1 : (zz == 2) ? s2 : s3;
  __bf16* out = (zz == 3) ? dwo : dqkv + (size_t)zz * D * D;
  const int c0 = blockIdx.x * 32, r0 = blockIdx.y * 32;
  const int tx = threadIdx.x & 31, ty = threadIdx.x >> 5;  // 32x8
#pragma unroll
  for (int i = 0; i < 32; i += 8)
    tile[ty + i][tx] = (__bf16)in[(size_t)(r0 + ty + i) * D + c0 + tx];
  __syncthreads();
  const int oc = threadIdx.x >> 3, rch = (threadIdx.x & 7) * 4;
  bf16x4 v;
#pragma unroll
  for (int j = 0; j < 4; j++) v[j] = tile[rch + j][oc];
  *(bf16x4*)(out + (size_t)(c0 + oc) * D + r0 + rch) = v;
}

__global__ __launch_bounds__(256) void k_concat_bias(const float* bq,
                                                     const float* bk,
                                                     const float* bv,
                                                     float* out) {
  const int i = blockIdx.x * 256 + threadIdx.x;
  if (i < D) { out[i] = bq[i]; out[D + i] = bk[i]; out[2 * D + i] = bv[i]; }
}

__global__ __launch_bounds__(256) void k_rope_table(float* __restrict__ ct,
                                                    float* __restrict__ st) {
  const int i = blockIdx.x * 256 + threadIdx.x;
  if (i < T * 64) {
    const int t = i >> 6, j = i & 63;
    const float inv = expf(-((float)(2 * j) * (1.f / 128.f)) * 9.210340371976184f);
    const float ang = (float)t * inv;
    ct[i] = cosf(ang);
    st[i] = sinf(ang);
  }
}

__global__ __launch_bounds__(256) void k_build_z(const int* __restrict__ tokens,
                                                 const float* __restrict__ embed,
                                                 const float* __restrict__ scratch,
                                                 float* __restrict__ z) {
  const int row = blockIdx.x;  // b*T + t
  const int b = row / T, t = row % T;
  const float* src = (t < S) ? embed + (size_t)tokens[b * S + t] * D
                             : scratch + (size_t)(t - S) * D;
  ((float4*)(z + (size_t)row * D))[threadIdx.x] =
      ((const float4*)src)[threadIdx.x];
}

// z (+= te), h = LN(z)*s + b  (bf16 out)
template <bool ADDT>
__global__ __launch_bounds__(256) void k_ln(float* __restrict__ z,
                                            const float* __restrict__ te,
                                            const float* __restrict__ gs,
                                            const float* __restrict__ gb,
                                            __bf16* __restrict__ h) {
  const int row = blockIdx.x, tid = threadIdx.x;
  float* zp = z + (size_t)row * D;
  float4 x = ((float4*)zp)[tid];
  if (ADDT) {
    const float4 t4 = ((const float4*)te)[tid];
    x.x += t4.x; x.y += t4.y; x.z += t4.z; x.w += t4.w;
    ((float4*)zp)[tid] = x;
  }
  float s = x.x + x.y + x.z + x.w;
  float s2 = x.x * x.x + x.y * x.y + x.z * x.z + x.w * x.w;
#pragma unroll
  for (int o = 32; o; o >>= 1) { s += __shfl_xor(s, o); s2 += __shfl_xor(s2, o); }
  __shared__ float rs[4], rq[4];
  const int wv = tid >> 6, ln = tid & 63;
  if (!ln) { rs[wv] = s; rq[wv] = s2; }
  __syncthreads();
  s = rs[0] + rs[1] + rs[2] + rs[3];
  s2 = rq[0] + rq[1] + rq[2] + rq[3];
  const float mu = s * (1.f / D);
  const float var = s2 * (1.f / D) - mu * mu;
  const float rinv = 1.0f / sqrtf(var + 1e-6f);
  const int c = tid * 4;
  const float4 g4 = ((const float4*)gs)[tid];
  const float4 b4 = ((const float4*)gb)[tid];
  bf16x4 o4;
  o4[0] = (__bf16)((x.x - mu) * rinv * g4.x + b4.x);
  o4[1] = (__bf16)((x.y - mu) * rinv * g4.y + b4.y);
  o4[2] = (__bf16)((x.z - mu) * rinv * g4.z + b4.z);
  o4[3] = (__bf16)((x.w - mu) * rinv * g4.w + b4.w);
  *(bf16x4*)(h + (size_t)row * D + c) = o4;
}

__global__ __launch_bounds__(256) void k_halt(const float* __restrict__ z,
                                              const float* __restrict__ hw,
                                              const float* __restrict__ hb,
                                              float* __restrict__ out) {
  const int b = blockIdx.x, tid = threadIdx.x;
  const float4 w4 = ((const float4*)hw)[tid];
  float acc = 0.f;
  for (int j = 0; j < SCR; j++) {
    const float4 x = ((const float4*)(z + ((size_t)(b * T + S + j)) * D))[tid];
    acc += x.x * w4.x + x.y * w4.y + x.z * w4.z + x.w * w4.w;
  }
#pragma unroll
  for (int o = 32; o; o >>= 1) acc += __shfl_xor(acc, o);
  __shared__ float rs[4];
  const int wv = tid >> 6, ln = tid & 63;
  if (!ln) rs[wv] = acc;
  __syncthreads();
  if (tid == 0) {
    const float tot = rs[0] + rs[1] + rs[2] + rs[3];
    out[b] = 1.f / (1.f + expf(-(tot * (1.f / SCR) + hb[0])));
  }
}

// compact cast: zb[b*S+s] = bf16(z[b*T+s]), only token rows
__global__ __launch_bounds__(256) void k_cast(const float* __restrict__ z,
                                              __bf16* __restrict__ zb) {
  const int row = blockIdx.x;            // b*S + s
  const int b = row >> 7, s = row & 127; // S = 128
  const float4 x = ((const float4*)(z + ((size_t)(b * T + s)) * D))[threadIdx.x];
  bf16x4 o;
  o[0] = (__bf16)x.x; o[1] = (__bf16)x.y; o[2] = (__bf16)x.z; o[3] = (__bf16)x.w;
  *(bf16x4*)(zb + (size_t)row * D + threadIdx.x * 4) = o;
}

// ---------------------------------------------------------------------------
extern "C" void kernel_launch(void* const* d_in, const int* in_sizes, int n_in,
                              void* d_out, int out_size, void* d_ws,
                              size_t ws_size, hipStream_t stream) {
  const int* tokens = (const int*)d_in[0];
  const float* embed = (const float*)d_in[1];
  const float* time_embed = (const float*)d_in[2];
  const float* scratch = (const float*)d_in[3];
  const float* wq = (const float*)d_in[4];  const float* bq = (const float*)d_in[5];
  const float* wk = (const float*)d_in[6];  const float* bk = (const float*)d_in[7];
  const float* wvv = (const float*)d_in[8]; const float* bv = (const float*)d_in[9];
  const float* wo = (const float*)d_in[10]; const float* bo = (const float*)d_in[11];
  const float* ln1s = (const float*)d_in[12]; const float* ln1b = (const float*)d_in[13];
  const float* ln2s = (const float*)d_in[14]; const float* ln2b = (const float*)d_in[15];
  const float* w1 = (const float*)d_in[16]; const float* b1 = (const float*)d_in[17];
  const float* w2 = (const float*)d_in[18]; const float* b2 = (const float*)d_in[19];
  const float* hw = (const float*)d_in[20]; const float* hb = (const float*)d_in[21];
  const float* dw = (const float*)d_in[22]; const float* db = (const float*)d_in[23];

  char* w = (char*)d_ws;
  size_t off = 0;
  auto al = [&](size_t n) { size_t o = off; off += (n + 255) & ~(size_t)255; return o; };
  const size_t oWqkvT = al((size_t)3 * D * D * 2);
  const size_t oWoT   = al((size_t)D * D * 2);
  const size_t oW1T   = al((size_t)DFF * D * 2);
  const size_t oW2T   = al((size_t)D * DFF * 2);
  const size_t oDecT  = al((size_t)V * D * 2);
  const size_t oBqkv  = al((size_t)3 * D * 4);
  const size_t oCt    = al((size_t)T * 64 * 4);
  const size_t oSt    = al((size_t)T * 64 * 4);
  const size_t oZ     = al((size_t)ROWS * D * 4);
  const size_t oH     = al((size_t)ROWS * D * 2);   // h; later zb alias
  const size_t oG     = al((size_t)ROWS * DFF * 2); // gelu out (bf16)
  const size_t oOB    = al((size_t)ROWS * D * 2);   // attn out packed (bf16)
  const size_t oQ     = al(QSZ * 2);
  const size_t oK     = al(QSZ * 2);
  const size_t oVT    = al(QSZ * 2);
  (void)ws_size; (void)in_sizes; (void)n_in; (void)out_size;

  __bf16* WqkvT = (__bf16*)(w + oWqkvT);
  __bf16* WoT   = (__bf16*)(w + oWoT);
  __bf16* W1T   = (__bf16*)(w + oW1T);
  __bf16* W2T   = (__bf16*)(w + oW2T);
  __bf16* DecT  = (__bf16*)(w + oDecT);
  float*  bqkv  = (float*)(w + oBqkv);
  float*  ct    = (float*)(w + oCt);
  float*  st    = (float*)(w + oSt);
  float*  z     = (float*)(w + oZ);
  __bf16* h     = (__bf16*)(w + oH);
  __bf16* g     = (__bf16*)(w + oG);
  __bf16* ob    = (__bf16*)(w + oOB);
  __bf16* qb    = (__bf16*)(w + oQ);    // qb|kb|vT contiguous (EPI=5 relies on QSZ offsets)
  __bf16* kb    = (__bf16*)(w + oK);
  __bf16* vT    = (__bf16*)(w + oVT);
  __bf16* zb    = (__bf16*)(w + oH);    // alias (h dead at decode time)

  float* logits = (float*)d_out;
  float* halts  = (float*)d_out + LOGITS;

  // --- weight prep (runs every call; deterministic) ---
  k_transpose4<<<dim3(32, 32, 4), 256, 0, stream>>>(wq, wk, wvv, wo, WqkvT, WoT);
  k_transpose<<<dim3(128, 32), 256, 0, stream>>>(w1, W1T, D, DFF);
  k_transpose<<<dim3(32, 128), 256, 0, stream>>>(w2, W2T, DFF, D);
  k_transpose<<<dim3((V + 31) / 32, 32), 256, 0, stream>>>(dw, DecT, D, V);
  k_concat_bias<<<4, 256, 0, stream>>>(bq, bk, bv, bqkv);
  k_rope_table<<<(T * 64 + 255) / 256, 256, 0, stream>>>(ct, st);
  k_build_z<<<ROWS, 256, 0, stream>>>(tokens, embed, scratch, z);

  for (int step = 0; step < NSTEP; step++) {
    k_ln<true><<<ROWS, 256, 0, stream>>>(z, time_embed + (size_t)step * D, ln1s, ln1b, h);
    // QKV (3072,1024)x(1024,3072) + rope fused -> qb/kb/vT directly
    k_gemm<5><<<dim3(24, 24, 1), 256, 65536, stream>>>(h, 0, D, ROWS, WqkvT, 0, D,
                                                       3 * D, D, bqkv, qb, 0, 0, ct, st);
    // fused attention: 2 blocks per (b,h), scores + softmax + PV -> ob
    k_attn<<<BB * H * 2, 128, 98304, stream>>>(qb, kb, vT, ob);
    // WO + residual into z
    k_gemm<1><<<dim3(8, 24, 1), 256, 65536, stream>>>(ob, 0, D, ROWS, WoT, 0, D, D,
                                                      D, bo, z, 0, D, nullptr, nullptr);
    k_ln<false><<<ROWS, 256, 0, stream>>>(z, nullptr, ln2s, ln2b, h);
    // MLP1 + gelu -> bf16
    k_gemm<2><<<dim3(32, 24, 1), 256, 65536, stream>>>(h, 0, D, ROWS, W1T, 0, D,
                                                       DFF, D, b1, g, 0, DFF, nullptr, nullptr);
    // MLP2 + residual into z: split-K=4 (chunks of 1024), atomicAdd epilogue
    k_gemm<4><<<dim3(8, 24, 4), 256, 65536, stream>>>(g, 0, DFF, ROWS, W2T, 0, DFF,
                                                      D, DFF / 4, b2, z, 0, D, nullptr, nullptr);
    k_halt<<<BB, 256, 0, stream>>>(z, hw, hb, halts + step * BB);
  }

  // decoder: one merged (2048,1024) x (1024,100277) GEMM, 256x256x64 tiles
  k_cast<<<MD, 256, 0, stream>>>(z, zb);
  k_dec<<<DEC_NWG, 512, 131072, stream>>>(zb, DecT, db, logits);
}

// Round 19
// 2694.648 us; speedup vs baseline: 1.0660x; 1.0045x over previous
//
#include <hip/hip_runtime.h>
#include <hip/hip_bf16.h>
#include <math.h>

// ---------------------------------------------------------------------------
// UniversalReasoner: 8-step recurrent transformer + vocab decoder, MI355X.
// Round 19:
//   - k_dec reverted to R17 form (R18 sectioning was -10us).
//   - te-fold: bote[s] = bo + te[s] precomputed; WO epilogue bias adds it,
//     k_ln<true> no longer writes z back (z stays pure; te enters the stream
//     via WO's residual add). Saves 12.6MB f32 store per step.
//   - everything else identical to R17 (best known 2705us config).
// ---------------------------------------------------------------------------

typedef float  f32x4  __attribute__((ext_vector_type(4)));
typedef __bf16 bf16x8 __attribute__((ext_vector_type(8)));
typedef __bf16 bf16x4 __attribute__((ext_vector_type(4)));

static constexpr int BB   = 16;     // batch
static constexpr int S    = 128;    // sequence tokens
static constexpr int SCR  = 64;     // scratch tokens
static constexpr int T    = 192;    // S + SCR
static constexpr int D    = 1024;
static constexpr int H    = 8;
static constexpr int HD   = 128;
static constexpr int DFF  = 4096;
static constexpr int NSTEP= 8;
static constexpr int V    = 100277;
static constexpr int ROWS = BB * T; // 3072
static constexpr int MD   = BB * S; // 2048 decoder rows
static constexpr long long LOGITS = (long long)BB * S * V; // 205367296
static constexpr size_t QSZ = (size_t)BB * H * T * HD;     // per q/k/v tensor

#define DEV __device__ __forceinline__

DEV void gload16(const __bf16* g, __bf16* l) {
  __builtin_amdgcn_global_load_lds(
      (__attribute__((address_space(1))) void*)(g),
      (__attribute__((address_space(3))) void*)(l), 16, 0, 0);
}

// ---------------------------------------------------------------------------
// Workhorse GEMM (128x128x64):  C[M,N] = A[M,K] * Bt[N,K]^T (+epilogue)
// EPI: 1 = bias + in-place f32 residual add ; 2 = bias + gelu -> bf16 ;
//      4 = split-K: bz = k-chunk, atomicAdd into f32 C, bias only on bz==0 ;
//      5 = QKV+rope: writes q/k bf16 (rope'd) and vT bf16 via kind = tn>>10.
// Requires K % 64 == 0. Launch with 65536 B dynamic LDS.
// ---------------------------------------------------------------------------
template <int EPI>
__global__ __launch_bounds__(256) void k_gemm(
    const __bf16* __restrict__ A, long long sA, int ldA, int M,
    const __bf16* __restrict__ Bt, long long sB, int ldB, int N, int K,
    const float* __restrict__ bias, void* __restrict__ C, long long sC,
    int ldC, const float* __restrict__ rct, const float* __restrict__ rst) {
  extern __shared__ char smem[];
  __bf16* lds = (__bf16*)smem;   // A(buf)=lds+buf*16384; B(buf)=+8192

  const int bz = blockIdx.z;
  const __bf16* Ab;
  const __bf16* Bb;
  if constexpr (EPI == 4) {
    Ab = A + (size_t)bz * K;   // k-chunk offset within row
    Bb = Bt + (size_t)bz * K;
  } else {
    Ab = A + (size_t)bz * sA;
    Bb = Bt + (size_t)bz * sB;
  }
  const int tm = blockIdx.y * 128, tn = blockIdx.x * 128;
  const int tid = threadIdx.x;
  const int lane = tid & 63, wv = tid >> 6;
  const int wr = wv >> 1, wc = wv & 1;  // 2x2 wave grid, 64x64 per wave
  const int g4 = lane >> 4, l15 = lane & 15;

  f32x4 acc[4][4];
#pragma unroll
  for (int m = 0; m < 4; m++)
#pragma unroll
    for (int n = 0; n < 4; n++) acc[m][n] = (f32x4)(0.f);

  // staging: chunk = i*256+tid -> local row = i*32 + (tid>>3), phys slot tid&7
  const int srow = tid >> 3;                          // 0..31
  const int lcol = (((tid & 7) ^ (srow & 7)) * 8);    // pre-swizzled k offset
  int arows[4], brows[4];
#pragma unroll
  for (int i = 0; i < 4; i++) {
    int ar = tm + i * 32 + srow; if (ar > M - 1) ar = M - 1;
    int br = tn + i * 32 + srow; if (br > N - 1) br = N - 1;
    arows[i] = ar; brows[i] = br;
  }

  auto stage = [&](int buf, int kk) {
    __bf16* Abuf = lds + buf * 16384;
    __bf16* Bbuf = lds + 8192 + buf * 16384;
#pragma unroll
    for (int i = 0; i < 4; i++)
      gload16(Ab + (size_t)arows[i] * ldA + kk + lcol, Abuf + i * 2048 + (size_t)tid * 8);
#pragma unroll
    for (int i = 0; i < 4; i++)
      gload16(Bb + (size_t)brows[i] * ldB + kk + lcol, Bbuf + i * 2048 + (size_t)tid * 8);
  };

  // one K-tile (64 wide): 2 sub-phases, 16 MFMA each (32 per wave).
  auto compute = [&](int cur) {
    const __bf16* Abuf = lds + cur * 16384;
    const __bf16* Bbuf = lds + 8192 + cur * 16384;
    bf16x8 af[4], bfv[4];
    // --- ks = 0 ---
#pragma unroll
    for (int m = 0; m < 4; m++) {
      const int row = wr * 64 + m * 16 + l15;
      af[m] = *(const bf16x8*)&Abuf[row * 64 + (g4 ^ (row & 7)) * 8];
    }
#pragma unroll
    for (int n = 0; n < 4; n++) {
      const int row = wc * 64 + n * 16 + l15;
      bfv[n] = *(const bf16x8*)&Bbuf[row * 64 + (g4 ^ (row & 7)) * 8];
    }
    asm volatile("s_waitcnt lgkmcnt(0)" ::: "memory");
    __builtin_amdgcn_sched_barrier(0);
#pragma unroll
    for (int m = 0; m < 4; m++)
#pragma unroll
      for (int n = 0; n < 4; n++)
        acc[m][n] = __builtin_amdgcn_mfma_f32_16x16x32_bf16(af[m], bfv[n],
                                                            acc[m][n], 0, 0, 0);
    // --- ks = 1 ---
#pragma unroll
    for (int m = 0; m < 4; m++) {
      const int row = wr * 64 + m * 16 + l15;
      af[m] = *(const bf16x8*)&Abuf[row * 64 + ((4 + g4) ^ (row & 7)) * 8];
    }
#pragma unroll
    for (int n = 0; n < 4; n++) {
      const int row = wc * 64 + n * 16 + l15;
      bfv[n] = *(const bf16x8*)&Bbuf[row * 64 + ((4 + g4) ^ (row & 7)) * 8];
    }
    asm volatile("s_waitcnt lgkmcnt(0)" ::: "memory");
    __builtin_amdgcn_sched_barrier(0);
    __builtin_amdgcn_s_barrier();   // all waves done reading buf[cur]
#pragma unroll
    for (int m = 0; m < 4; m++)
#pragma unroll
      for (int n = 0; n < 4; n++)
        acc[m][n] = __builtin_amdgcn_mfma_f32_16x16x32_bf16(af[m], bfv[n],
                                                            acc[m][n], 0, 0, 0);
  };

  const int NT = K >> 6;           // K-tiles of 64 (K % 64 == 0)
  stage(0, 0);
  for (int it = 0; it < NT - 1; ++it) {
    const int cur = it & 1;
    stage(cur ^ 1, (it + 1) << 6);                    // 8 loads in flight
    asm volatile("s_waitcnt vmcnt(8)" ::: "memory");  // tile-cur loads landed
    __builtin_amdgcn_s_barrier();
    compute(cur);
  }
  asm volatile("s_waitcnt vmcnt(0)" ::: "memory");
  __builtin_amdgcn_s_barrier();
  compute((NT - 1) & 1);

  // epilogue: C/D layout col=lane&15, row=(lane>>4)*4+reg
  const int r0 = tm + wr * 64, c0 = tn + wc * 64;
  if constexpr (EPI == 5) {
    const int kind = tn >> 10;  // 0=q, 1=k, 2=v
#pragma unroll
    for (int n = 0; n < 4; n++) {
      const int c = c0 + n * 16 + (lane & 15);
      const int hh = (c & 1023) >> 7, d = c & 127, jp = d >> 1;
      const float bsv = bias[c];
#pragma unroll
      for (int m = 0; m < 4; m++) {
        const int rb = r0 + m * 16 + ((lane >> 4) << 2);
#pragma unroll
        for (int j = 0; j < 4; j++) {
          const int r = rb + j;
          const float x = acc[m][n][j] + bsv;
          const float xo = __shfl_xor(x, 1);   // pair value (col ^ 1)
          const int b = r / T, t = r % T;
          if (kind == 2) {
            ((__bf16*)C)[2 * QSZ + ((size_t)((b * H + hh) * HD + d)) * T + t] =
                (__bf16)x;
          } else {
            const float cs = rct[t * 64 + jp], sn = rst[t * 64 + jp];
            const float o = (c & 1) ? (x * cs + xo * sn) : (x * cs - xo * sn);
            ((__bf16*)C)[(size_t)kind * QSZ +
                         ((size_t)((b * H + hh) * T + t)) * HD + d] = (__bf16)o;
          }
        }
      }
    }
    return;
  }
#pragma unroll
  for (int n = 0; n < 4; n++) {
    const int c = c0 + n * 16 + (lane & 15);
    if (c >= N) continue;
    const float bsv = (bias && (EPI != 4 || bz == 0)) ? bias[c] : 0.f;
#pragma unroll
    for (int m = 0; m < 4; m++) {
      const int rb = r0 + m * 16 + ((lane >> 4) << 2);
#pragma unroll
      for (int j = 0; j < 4; j++) {
        const int r = rb + j;
        if (r >= M) continue;
        float x = acc[m][n][j] + bsv;
        if constexpr (EPI == 4) {
          atomicAdd((float*)C + (size_t)r * ldC + c, x);
        } else {
          const size_t idx = (size_t)bz * sC + (size_t)r * ldC + c;
          if constexpr (EPI == 2) {
            const float u = x;
            const float gl =
                0.5f * u * (1.f + tanhf(0.7978845608f * (u + 0.044715f * u * u * u)));
            ((__bf16*)C)[idx] = (__bf16)gl;
          } else {
            ((float*)C)[idx] += x;
          }
        }
      }
    }
  }
}

// ---------------------------------------------------------------------------
// Fused attention: 2 blocks per (b,h) (Q-halves), 128 thr / 2 waves x 48 rows.
// LDS: K [192][128] swz (48KB, overlaid by P [96][192] after barrier);
//      V^T 3 x [128][64] swz at +49152. dyn 98304 B.
// ---------------------------------------------------------------------------
__global__ __launch_bounds__(128) void k_attn(const __bf16* __restrict__ qb,
                                              const __bf16* __restrict__ kb,
                                              const __bf16* __restrict__ vT,
                                              __bf16* __restrict__ ob) {
  extern __shared__ char smem[];
  __bf16* Kl = (__bf16*)smem;             // [192][128]
  __bf16* Pl = (__bf16*)smem;             // [96][192] (after barrier)
  __bf16* Vl = (__bf16*)(smem + 49152);   // 3 x [128][64]
  const int bid = blockIdx.x;
  const int bh = bid >> 1, q0 = (bid & 1) * 96;   // Q-half base (96 % 8 == 0)
  const int tid = threadIdx.x, lane = tid & 63, wv = tid >> 6;  // wv in {0,1}
  const int g4 = lane >> 4, l15 = lane & 15;
  const size_t hoff = (size_t)bh * T * HD;
  const size_t voff = (size_t)bh * HD * T;

  // --- hoist Q fragments (regs) ---
  bf16x8 qf[3][4];
#pragma unroll
  for (int m = 0; m < 3; m++)
#pragma unroll
    for (int ks = 0; ks < 4; ks++) {
      const int tq = q0 + wv * 48 + m * 16 + l15;
      qf[m][ks] = *(const bf16x8*)(qb + hoff + (size_t)tq * HD + ks * 32 + g4 * 8);
    }

  // --- stage K: 48 chunks (24/wave) of 4 rows x 16 slots(16B), swz source ---
#pragma unroll
  for (int ci = 0; ci < 24; ci++) {
    const int ch = wv * 24 + ci;
    const int grow = ch * 4 + g4;
    const int sl = l15 ^ (grow & 7);
    gload16(kb + hoff + (size_t)grow * HD + sl * 8, Kl + ch * 512);
  }
  // --- stage V^T: 3 subtiles x 16 chunks (24/wave) of 8 rows x 8 slots ---
#pragma unroll
  for (int ci = 0; ci < 24; ci++) {
    const int ch = wv * 24 + ci;
    const int c = ch >> 4, ch2 = ch & 15;
    const int d = ch2 * 8 + (lane >> 3);
    const int sl = (lane & 7) ^ (d & 7);
    gload16(vT + voff + (size_t)d * T + c * 64 + sl * 8,
            Vl + c * 8192 + ch2 * 512);
  }
  asm volatile("s_waitcnt vmcnt(0)" ::: "memory");
  __builtin_amdgcn_s_barrier();

  // --- S = Q K^T ---
  f32x4 sacc[3][12];
#pragma unroll
  for (int m = 0; m < 3; m++)
#pragma unroll
    for (int nf = 0; nf < 12; nf++) sacc[m][nf] = (f32x4)(0.f);
#pragma unroll
  for (int ks = 0; ks < 4; ks++)
#pragma unroll
    for (int nf = 0; nf < 12; nf++) {
      const int row = nf * 16 + l15;
      const int sl = (ks * 4 + g4) ^ (row & 7);
      const bf16x8 kf = *(const bf16x8*)&Kl[row * 128 + sl * 8];
#pragma unroll
      for (int m = 0; m < 3; m++)
        sacc[m][nf] = __builtin_amdgcn_mfma_f32_16x16x32_bf16(qf[m][ks], kf,
                                                              sacc[m][nf], 0, 0, 0);
    }

  // --- softmax (scale, causal mask, in-reg row reduce) ---
  const float scale = 0.08838834764831845f;
  float inv[3][4];
#pragma unroll
  for (int m = 0; m < 3; m++)
#pragma unroll
    for (int j = 0; j < 4; j++) {
      const int tq = q0 + wv * 48 + m * 16 + g4 * 4 + j;
#pragma unroll
      for (int nf = 0; nf < 12; nf++) {
        const int c = nf * 16 + l15;
        float v = sacc[m][nf][j] * scale;
        if (tq < S && c > tq) v = -1e30f;
        sacc[m][nf][j] = v;
      }
      float mm = -1e30f;
#pragma unroll
      for (int nf = 0; nf < 12; nf++) mm = fmaxf(mm, sacc[m][nf][j]);
#pragma unroll
      for (int o = 1; o < 16; o <<= 1) mm = fmaxf(mm, __shfl_xor(mm, o));
      float sum = 0.f;
#pragma unroll
      for (int nf = 0; nf < 12; nf++) {
        const float e = __expf(sacc[m][nf][j] - mm);
        sacc[m][nf][j] = e;
        sum += e;
      }
#pragma unroll
      for (int o = 1; o < 16; o <<= 1) sum += __shfl_xor(sum, o);
      inv[m][j] = 1.f / sum;
    }

  // --- P to LDS (overlays K; all waves' K reads complete first) ---
  __builtin_amdgcn_s_barrier();
#pragma unroll
  for (int m = 0; m < 3; m++)
#pragma unroll
    for (int nf = 0; nf < 12; nf++)
#pragma unroll
      for (int j = 0; j < 4; j++) {
        const int q = wv * 48 + m * 16 + g4 * 4 + j;   // local 0..95
        const int c = nf * 16 + l15;
        Pl[q * 192 + (((c >> 3) ^ (q & 7)) * 8) + (c & 7)] =
            (__bf16)(sacc[m][nf][j] * inv[m][j]);
      }
  asm volatile("s_waitcnt lgkmcnt(0)" ::: "memory");
  __builtin_amdgcn_sched_barrier(0);
  __builtin_amdgcn_s_barrier();   // P complete before cross-wave PV reads

  // --- O = P V (wave-local P rows) ---
  f32x4 oacc[3][8];
#pragma unroll
  for (int m = 0; m < 3; m++)
#pragma unroll
    for (int nf = 0; nf < 8; nf++) oacc[m][nf] = (f32x4)(0.f);
#pragma unroll
  for (int ks = 0; ks < 6; ks++) {
    bf16x8 pf[3];
#pragma unroll
    for (int m = 0; m < 3; m++) {
      const int q = wv * 48 + m * 16 + l15;            // local
      const int sl = (ks * 4 + g4) ^ (q & 7);
      pf[m] = *(const bf16x8*)&Pl[q * 192 + sl * 8];
    }
#pragma unroll
    for (int nf = 0; nf < 8; nf++) {
      const int d = nf * 16 + l15;
      const int sl = ((ks & 1) * 4 + g4) ^ (d & 7);
      const bf16x8 vf = *(const bf16x8*)&Vl[(ks >> 1) * 8192 + d * 64 + sl * 8];
#pragma unroll
      for (int m = 0; m < 3; m++)
        oacc[m][nf] = __builtin_amdgcn_mfma_f32_16x16x32_bf16(pf[m], vf,
                                                              oacc[m][nf], 0, 0, 0);
    }
  }

  // --- write O into packed ob layout ---
  const int b = bh >> 3, hh = bh & 7;
#pragma unroll
  for (int m = 0; m < 3; m++)
#pragma unroll
    for (int nf = 0; nf < 8; nf++) {
      const int d = nf * 16 + l15;
#pragma unroll
      for (int j = 0; j < 4; j++) {
        const int tq = q0 + wv * 48 + m * 16 + g4 * 4 + j;
        ob[((size_t)(b * T + tq)) * D + hh * HD + d] = (__bf16)oacc[m][nf][j];
      }
    }
}

// ---------------------------------------------------------------------------
// Decoder GEMM: logits[MD,V] = zb[MD,D] * DecT[V,D]^T + db.
// 256x256x64 tile, 512 thr / 8 waves (2Mx4N), 128KB dynamic LDS, 2-buffer
// counted-vmcnt(8), 2 MFMA sub-phases per K-tile; XCD-chunked M-fastest
// swizzle; 4-pass LDS-staged f32 epilogue (full 128B lines).
// ---------------------------------------------------------------------------
static constexpr int DEC_NT = (V + 255) / 256;        // 392
static constexpr int DEC_NWG = 8 * DEC_NT;            // 3136 (div by 8)

__global__ __launch_bounds__(512, 2) void k_dec(const __bf16* __restrict__ A,
                                                const __bf16* __restrict__ Bt,
                                                const float* __restrict__ bias,
                                                float* __restrict__ C) {
  extern __shared__ char smem[];
  __bf16* lds = (__bf16*)smem;         // 65536 bf16 = 128 KB
  float* cbuf = (float*)smem;          // epilogue alias: 64 x 256 f32 (64 KB)

  const int bid = blockIdx.x;
  const int swz = (bid & 7) * DEC_NT + (bid >> 3);
  const int tm = (swz & 7) * 256, tn = (swz >> 3) * 256;
  const int tid = threadIdx.x;
  const int lane = tid & 63, wv = tid >> 6;
  const int wm = wv >> 2, wn = wv & 3;         // 2x4 wave grid, 128x64 each
  const int g4 = lane >> 4, l15 = lane & 15;

  f32x4 acc[8][4];
#pragma unroll
  for (int m = 0; m < 8; m++)
#pragma unroll
    for (int n = 0; n < 4; n++) acc[m][n] = (f32x4)(0.f);

  // staging: round i: local row = (tid>>3)+i*64, phys 16B-slot = tid&7,
  // logical k-slot = (tid&7)^(row&7) -> pre-swizzled global k offset.
  const int srow = tid >> 3;                          // 0..63
  const int lcol = (((tid & 7) ^ (srow & 7)) * 8);    // bf16 elems
  int arows[4], brows[4];
#pragma unroll
  for (int i = 0; i < 4; i++) {
    arows[i] = tm + i * 64 + srow;                    // M=2048, in range
    int br = tn + i * 64 + srow; if (br > V - 1) br = V - 1;
    brows[i] = br;
  }

  auto stage = [&](int buf, int kk) {
    __bf16* Abuf = lds + buf * 32768;
    __bf16* Bbuf = lds + 16384 + buf * 32768;
#pragma unroll
    for (int i = 0; i < 4; i++)
      gload16(A + (size_t)arows[i] * D + kk + lcol, Abuf + i * 4096 + (size_t)tid * 8);
#pragma unroll
    for (int i = 0; i < 4; i++)
      gload16(Bt + (size_t)brows[i] * D + kk + lcol, Bbuf + i * 4096 + (size_t)tid * 8);
  };

  // compute one K-tile (64 wide): 2 sub-phases (ks=0,1), 32 MFMA each.
  auto compute = [&](int cur) {
    const __bf16* Abuf = lds + cur * 32768;
    const __bf16* Bbuf = lds + 16384 + cur * 32768;
    bf16x8 af[8], bfv[4];
    // --- ks = 0 ---
#pragma unroll
    for (int m = 0; m < 8; m++) {
      const int row = wm * 128 + m * 16 + l15;
      af[m] = *(const bf16x8*)&Abuf[row * 64 + (g4 ^ (row & 7)) * 8];
    }
#pragma unroll
    for (int n = 0; n < 4; n++) {
      const int row = wn * 64 + n * 16 + l15;
      bfv[n] = *(const bf16x8*)&Bbuf[row * 64 + (g4 ^ (row & 7)) * 8];
    }
    asm volatile("s_waitcnt lgkmcnt(0)" ::: "memory");
    __builtin_amdgcn_sched_barrier(0);
#pragma unroll
    for (int m = 0; m < 8; m++)
#pragma unroll
      for (int n = 0; n < 4; n++)
        acc[m][n] = __builtin_amdgcn_mfma_f32_16x16x32_bf16(af[m], bfv[n],
                                                            acc[m][n], 0, 0, 0);
    // --- ks = 1 ---
#pragma unroll
    for (int m = 0; m < 8; m++) {
      const int row = wm * 128 + m * 16 + l15;
      af[m] = *(const bf16x8*)&Abuf[row * 64 + ((4 + g4) ^ (row & 7)) * 8];
    }
#pragma unroll
    for (int n = 0; n < 4; n++) {
      const int row = wn * 64 + n * 16 + l15;
      bfv[n] = *(const bf16x8*)&Bbuf[row * 64 + ((4 + g4) ^ (row & 7)) * 8];
    }
    asm volatile("s_waitcnt lgkmcnt(0)" ::: "memory");
    __builtin_amdgcn_sched_barrier(0);
    __builtin_amdgcn_s_barrier();   // all waves done reading buf[cur]
#pragma unroll
    for (int m = 0; m < 8; m++)
#pragma unroll
      for (int n = 0; n < 4; n++)
        acc[m][n] = __builtin_amdgcn_mfma_f32_16x16x32_bf16(af[m], bfv[n],
                                                            acc[m][n], 0, 0, 0);
  };

  const int NT = D / 64;           // 16 K-tiles
  stage(0, 0);
  for (int it = 0; it < NT - 1; ++it) {
    const int cur = it & 1;
    stage(cur ^ 1, (it + 1) << 6);                    // 8 loads in flight
    asm volatile("s_waitcnt vmcnt(8)" ::: "memory");  // tile-cur loads landed
    __builtin_amdgcn_s_barrier();
    compute(cur);
  }
  asm volatile("s_waitcnt vmcnt(0)" ::: "memory");
  __builtin_amdgcn_s_barrier();
  compute((NT - 1) & 1);
  __syncthreads();   // all waves past compute barrier; cbuf aliasing safe

  // --- LDS-staged epilogue: 4 passes of 64 rows x 256 cols, full-line stores
  const bool full = (tn + 256 <= V);
  for (int pass = 0; pass < 4; ++pass) {
    if (pass) __syncthreads();           // prior pass reads done
    if (wm == (pass >> 1)) {
      const int mfb = (pass & 1) * 4;
#pragma unroll
      for (int n = 0; n < 4; n++) {
        const int col = wn * 64 + n * 16 + l15;
        const float bsv = (tn + col < V) ? bias[tn + col] : 0.f;
#pragma unroll
        for (int m2 = 0; m2 < 4; m2++) {
#pragma unroll
          for (int j = 0; j < 4; j++) {
            const int row = m2 * 16 + g4 * 4 + j;           // 0..63 in pass
            const int phys = (col >> 2) ^ (row & 7);        // 16B-slot swz
            cbuf[row * 256 + phys * 4 + (col & 3)] = acc[mfb + m2][n][j] + bsv;
          }
        }
      }
    }
    __syncthreads();
    const int rbase = tm + pass * 64;
    if (full) {
      const int row = tid >> 3, c8 = tid & 7;               // 64 rows x 8 lanes
#pragma unroll
      for (int i = 0; i < 8; ++i) {
        const int ps = (c8 ^ (row & 7)) + i * 8;            // phys slot
        const f32x4 v = *(const f32x4*)&cbuf[row * 256 + ps * 4];
        *(f32x4*)&C[(size_t)(rbase + row) * V + tn + (c8 + i * 8) * 4] = v;
      }
    } else {
      for (int idx = tid; idx < 64 * 256; idx += 512) {
        const int row = idx >> 8, col = idx & 255;
        if (tn + col < V)
          C[(size_t)(rbase + row) * V + tn + col] =
              cbuf[row * 256 + (((col >> 2) ^ (row & 7)) << 2) + (col & 3)];
      }
    }
  }
}

// ---------------------------------------------------------------------------
// transpose-cast: in f32 (R,C) -> out bf16 (C,R); vectorized bf16x4 stores.
// ---------------------------------------------------------------------------
__global__ __launch_bounds__(256) void k_transpose(const float* __restrict__ in,
                                                   __bf16* __restrict__ out,
                                                   int R, int C) {
  __shared__ __bf16 tile[32][33];
  const int c0 = blockIdx.x * 32, r0 = blockIdx.y * 32;
  const int tx = threadIdx.x & 31, ty = threadIdx.x >> 5;  // 32x8
#pragma unroll
  for (int i = 0; i < 32; i += 8) {
    const int r = r0 + ty + i, c = c0 + tx;
    tile[ty + i][tx] = (r < R && c < C) ? (__bf16)in[(size_t)r * C + c] : (__bf16)0.f;
  }
  __syncthreads();
  const int oc = threadIdx.x >> 3, rch = (threadIdx.x & 7) * 4;
  const int occ = c0 + oc, orr = r0 + rch;
  if (occ < C && orr + 3 < R) {
    bf16x4 v;
#pragma unroll
    for (int j = 0; j < 4; j++) v[j] = tile[rch + j][oc];
    *(bf16x4*)(out + (size_t)occ * R + orr) = v;
  }
}

// batched (1024,1024) transpose-cast: z selects {wq,wk,wv,wo}; first three
// go to WqkvT slabs, wo to WoT.
__global__ __launch_bounds__(256) void k_transpose4(const float* __restrict__ s0,
                                                    const float* __restrict__ s1,
                                                    const float* __restrict__ s2,
                                                    const float* __restrict__ s3,
                                                    __bf16* __restrict__ dqkv,
                                                    __bf16* __restrict__ dwo) {
  __shared__ __bf16 tile[32][33];
  const int zz = blockIdx.z;
  const float* in = (zz == 0) ? s0 : (zz == 1) ? s1 : (zz == 2) ? s2 : s3;
  __bf16* out = (zz == 3) ? dwo : dqkv + (size_t)zz * D * D;
  const int c0 = blockIdx.x * 32, r0 = blockIdx.y * 32;
  const int tx = threadIdx.x & 31, ty = threadIdx.x >> 5;  // 32x8
#pragma unroll
  for (int i = 0; i < 32; i += 8)
    tile[ty + i][tx] = (__bf16)in[(size_t)(r0 + ty + i) * D + c0 + tx];
  __syncthreads();
  const int oc = threadIdx.x >> 3, rch = (threadIdx.x & 7) * 4;
  bf16x4 v;
#pragma unroll
  for (int j = 0; j < 4; j++) v[j] = tile[rch + j][oc];
  *(bf16x4*)(out + (size_t)(c0 + oc) * D + r0 + rch) = v;
}

__global__ __launch_bounds__(256) void k_concat_bias(const float* bq,
                                                     const float* bk,
                                                     const float* bv,
                                                     float* out) {
  const int i = blockIdx.x * 256 + threadIdx.x;
  if (i < D) { out[i] = bq[i]; out[D + i] = bk[i]; out[2 * D + i] = bv[i]; }
}

// bote[s][c] = bo[c] + te[s][c], s in [0,NSTEP)
__global__ __launch_bounds__(256) void k_bote(const float* __restrict__ bo,
                                              const float* __restrict__ te,
                                              float* __restrict__ out) {
  const int i = blockIdx.x * 256 + threadIdx.x;
  if (i < NSTEP * D) out[i] = bo[i & (D - 1)] + te[i];
}

__global__ __launch_bounds__(256) void k_rope_table(float* __restrict__ ct,
                                                    float* __restrict__ st) {
  const int i = blockIdx.x * 256 + threadIdx.x;
  if (i < T * 64) {
    const int t = i >> 6, j = i & 63;
    const float inv = expf(-((float)(2 * j) * (1.f / 128.f)) * 9.210340371976184f);
    const float ang = (float)t * inv;
    ct[i] = cosf(ang);
    st[i] = sinf(ang);
  }
}

__global__ __launch_bounds__(256) void k_build_z(const int* __restrict__ tokens,
                                                 const float* __restrict__ embed,
                                                 const float* __restrict__ scratch,
                                                 float* __restrict__ z) {
  const int row = blockIdx.x;  // b*T + t
  const int b = row / T, t = row % T;
  const float* src = (t < S) ? embed + (size_t)tokens[b * S + t] * D
                             : scratch + (size_t)(t - S) * D;
  ((float4*)(z + (size_t)row * D))[threadIdx.x] =
      ((const float4*)src)[threadIdx.x];
}

// h = LN(z (+ te))*s + b  (bf16 out). ADDT: te added in registers only
// (z NOT written back; te enters the stream via WO's bote bias).
template <bool ADDT>
__global__ __launch_bounds__(256) void k_ln(const float* __restrict__ z,
                                            const float* __restrict__ te,
                                            const float* __restrict__ gs,
                                            const float* __restrict__ gb,
                                            __bf16* __restrict__ h) {
  const int row = blockIdx.x, tid = threadIdx.x;
  const float* zp = z + (size_t)row * D;
  float4 x = ((const float4*)zp)[tid];
  if (ADDT) {
    const float4 t4 = ((const float4*)te)[tid];
    x.x += t4.x; x.y += t4.y; x.z += t4.z; x.w += t4.w;
  }
  float s = x.x + x.y + x.z + x.w;
  float s2 = x.x * x.x + x.y * x.y + x.z * x.z + x.w * x.w;
#pragma unroll
  for (int o = 32; o; o >>= 1) { s += __shfl_xor(s, o); s2 += __shfl_xor(s2, o); }
  __shared__ float rs[4], rq[4];
  const int wv = tid >> 6, ln = tid & 63;
  if (!ln) { rs[wv] = s; rq[wv] = s2; }
  __syncthreads();
  s = rs[0] + rs[1] + rs[2] + rs[3];
  s2 = rq[0] + rq[1] + rq[2] + rq[3];
  const float mu = s * (1.f / D);
  const float var = s2 * (1.f / D) - mu * mu;
  const float rinv = 1.0f / sqrtf(var + 1e-6f);
  const int c = tid * 4;
  const float4 g4 = ((const float4*)gs)[tid];
  const float4 b4 = ((const float4*)gb)[tid];
  bf16x4 o4;
  o4[0] = (__bf16)((x.x - mu) * rinv * g4.x + b4.x);
  o4[1] = (__bf16)((x.y - mu) * rinv * g4.y + b4.y);
  o4[2] = (__bf16)((x.z - mu) * rinv * g4.z + b4.z);
  o4[3] = (__bf16)((x.w - mu) * rinv * g4.w + b4.w);
  *(bf16x4*)(h + (size_t)row * D + c) = o4;
}

__global__ __launch_bounds__(256) void k_halt(const float* __restrict__ z,
                                              const float* __restrict__ hw,
                                              const float* __restrict__ hb,
                                              float* __restrict__ out) {
  const int b = blockIdx.x, tid = threadIdx.x;
  const float4 w4 = ((const float4*)hw)[tid];
  float acc = 0.f;
  for (int j = 0; j < SCR; j++) {
    const float4 x = ((const float4*)(z + ((size_t)(b * T + S + j)) * D))[tid];
    acc += x.x * w4.x + x.y * w4.y + x.z * w4.z + x.w * w4.w;
  }
#pragma unroll
  for (int o = 32; o; o >>= 1) acc += __shfl_xor(acc, o);
  __shared__ float rs[4];
  const int wv = tid >> 6, ln = tid & 63;
  if (!ln) rs[wv] = acc;
  __syncthreads();
  if (tid == 0) {
    const float tot = rs[0] + rs[1] + rs[2] + rs[3];
    out[b] = 1.f / (1.f + expf(-(tot * (1.f / SCR) + hb[0])));
  }
}

// compact cast: zb[b*S+s] = bf16(z[b*T+s]), only token rows
__global__ __launch_bounds__(256) void k_cast(const float* __restrict__ z,
                                              __bf16* __restrict__ zb) {
  const int row = blockIdx.x;            // b*S + s
  const int b = row >> 7, s = row & 127; // S = 128
  const float4 x = ((const float4*)(z + ((size_t)(b * T + s)) * D))[threadIdx.x];
  bf16x4 o;
  o[0] = (__bf16)x.x; o[1] = (__bf16)x.y; o[2] = (__bf16)x.z; o[3] = (__bf16)x.w;
  *(bf16x4*)(zb + (size_t)row * D + threadIdx.x * 4) = o;
}

// ---------------------------------------------------------------------------
extern "C" void kernel_launch(void* const* d_in, const int* in_sizes, int n_in,
                              void* d_out, int out_size, void* d_ws,
                              size_t ws_size, hipStream_t stream) {
  const int* tokens = (const int*)d_in[0];
  const float* embed = (const float*)d_in[1];
  const float* time_embed = (const float*)d_in[2];
  const float* scratch = (const float*)d_in[3];
  const float* wq = (const float*)d_in[4];  const float* bq = (const float*)d_in[5];
  const float* wk = (const float*)d_in[6];  const float* bk = (const float*)d_in[7];
  const float* wvv = (const float*)d_in[8]; const float* bv = (const float*)d_in[9];
  const float* wo = (const float*)d_in[10]; const float* bo = (const float*)d_in[11];
  const float* ln1s = (const float*)d_in[12]; const float* ln1b = (const float*)d_in[13];
  const float* ln2s = (const float*)d_in[14]; const float* ln2b = (const float*)d_in[15];
  const float* w1 = (const float*)d_in[16]; const float* b1 = (const float*)d_in[17];
  const float* w2 = (const float*)d_in[18]; const float* b2 = (const float*)d_in[19];
  const float* hw = (const float*)d_in[20]; const float* hb = (const float*)d_in[21];
  const float* dw = (const float*)d_in[22]; const float* db = (const float*)d_in[23];

  char* w = (char*)d_ws;
  size_t off = 0;
  auto al = [&](size_t n) { size_t o = off; off += (n + 255) & ~(size_t)255; return o; };
  const size_t oWqkvT = al((size_t)3 * D * D * 2);
  const size_t oWoT   = al((size_t)D * D * 2);
  const size_t oW1T   = al((size_t)DFF * D * 2);
  const size_t oW2T   = al((size_t)D * DFF * 2);
  const size_t oDecT  = al((size_t)V * D * 2);
  const size_t oBqkv  = al((size_t)3 * D * 4);
  const size_t oBote  = al((size_t)NSTEP * D * 4);
  const size_t oCt    = al((size_t)T * 64 * 4);
  const size_t oSt    = al((size_t)T * 64 * 4);
  const size_t oZ     = al((size_t)ROWS * D * 4);
  const size_t oH     = al((size_t)ROWS * D * 2);   // h; later zb alias
  const size_t oG     = al((size_t)ROWS * DFF * 2); // gelu out (bf16)
  const size_t oOB    = al((size_t)ROWS * D * 2);   // attn out packed (bf16)
  const size_t oQ     = al(QSZ * 2);
  const size_t oK     = al(QSZ * 2);
  const size_t oVT    = al(QSZ * 2);
  (void)ws_size; (void)in_sizes; (void)n_in; (void)out_size;

  __bf16* WqkvT = (__bf16*)(w + oWqkvT);
  __bf16* WoT   = (__bf16*)(w + oWoT);
  __bf16* W1T   = (__bf16*)(w + oW1T);
  __bf16* W2T   = (__bf16*)(w + oW2T);
  __bf16* DecT  = (__bf16*)(w + oDecT);
  float*  bqkv  = (float*)(w + oBqkv);
  float*  bote  = (float*)(w + oBote);
  float*  ct    = (float*)(w + oCt);
  float*  st    = (float*)(w + oSt);
  float*  z     = (float*)(w + oZ);
  __bf16* h     = (__bf16*)(w + oH);
  __bf16* g     = (__bf16*)(w + oG);
  __bf16* ob    = (__bf16*)(w + oOB);
  __bf16* qb    = (__bf16*)(w + oQ);    // qb|kb|vT contiguous (EPI=5 relies on QSZ offsets)
  __bf16* kb    = (__bf16*)(w + oK);
  __bf16* vT    = (__bf16*)(w + oVT);
  __bf16* zb    = (__bf16*)(w + oH);    // alias (h dead at decode time)

  float* logits = (float*)d_out;
  float* halts  = (float*)d_out + LOGITS;

  // --- weight prep (runs every call; deterministic) ---
  k_transpose4<<<dim3(32, 32, 4), 256, 0, stream>>>(wq, wk, wvv, wo, WqkvT, WoT);
  k_transpose<<<dim3(128, 32), 256, 0, stream>>>(w1, W1T, D, DFF);
  k_transpose<<<dim3(32, 128), 256, 0, stream>>>(w2, W2T, DFF, D);
  k_transpose<<<dim3((V + 31) / 32, 32), 256, 0, stream>>>(dw, DecT, D, V);
  k_concat_bias<<<4, 256, 0, stream>>>(bq, bk, bv, bqkv);
  k_bote<<<(NSTEP * D + 255) / 256, 256, 0, stream>>>(bo, time_embed, bote);
  k_rope_table<<<(T * 64 + 255) / 256, 256, 0, stream>>>(ct, st);
  k_build_z<<<ROWS, 256, 0, stream>>>(tokens, embed, scratch, z);

  for (int step = 0; step < NSTEP; step++) {
    // LN1 over z+te (te in registers only; z unchanged in memory)
    k_ln<true><<<ROWS, 256, 0, stream>>>(z, time_embed + (size_t)step * D, ln1s, ln1b, h);
    // QKV (3072,1024)x(1024,3072) + rope fused -> qb/kb/vT directly
    k_gemm<5><<<dim3(24, 24, 1), 256, 65536, stream>>>(h, 0, D, ROWS, WqkvT, 0, D,
                                                       3 * D, D, bqkv, qb, 0, 0, ct, st);
    // fused attention: 2 blocks per (b,h), scores + softmax + PV -> ob
    k_attn<<<BB * H * 2, 128, 98304, stream>>>(qb, kb, vT, ob);
    // WO + residual into z, bias = bo + te[step] (te-fold)
    k_gemm<1><<<dim3(8, 24, 1), 256, 65536, stream>>>(ob, 0, D, ROWS, WoT, 0, D, D,
                                                      D, bote + (size_t)step * D,
                                                      z, 0, D, nullptr, nullptr);
    k_ln<false><<<ROWS, 256, 0, stream>>>(z, nullptr, ln2s, ln2b, h);
    // MLP1 + gelu -> bf16
    k_gemm<2><<<dim3(32, 24, 1), 256, 65536, stream>>>(h, 0, D, ROWS, W1T, 0, D,
                                                       DFF, D, b1, g, 0, DFF, nullptr, nullptr);
    // MLP2 + residual into z: split-K=4 (chunks of 1024), atomicAdd epilogue
    k_gemm<4><<<dim3(8, 24, 4), 256, 65536, stream>>>(g, 0, DFF, ROWS, W2T, 0, DFF,
                                                      D, DFF / 4, b2, z, 0, D, nullptr, nullptr);
    k_halt<<<BB, 256, 0, stream>>>(z, hw, hb, halts + step * BB);
  }

  // decoder: one merged (2048,1024) x (1024,100277) GEMM, 256x256x64 tiles
  k_cast<<<MD, 256, 0, stream>>>(z, zb);
  k_dec<<<DEC_NWG, 512, 131072, stream>>>(zb, DecT, db, logits);
}